// Round 9
// baseline (326.606 us; speedup 1.0000x reference)
//
#include <hip/hip_runtime.h>

#define NB 256        // partition blocks (1 per CU)
#define NWMAX 16384   // max packed words (n <= 65532); n=50000 -> NW=12500

// bf16 round-to-nearest-even helpers
__device__ __forceinline__ unsigned bfr(float x) {
    unsigned u = __float_as_uint(x);
    return (u + 0x7FFFu + ((u >> 16) & 1u)) >> 16;
}
__device__ __forceinline__ unsigned pack2(float lo, float hi) {
    return bfr(lo) | (bfr(hi) << 16);
}
__device__ __forceinline__ float ubf_lo(unsigned q) { return __uint_as_float(q << 16); }
__device__ __forceinline__ float ubf_hi(unsigned q) { return __uint_as_float(q & 0xFFFF0000u); }

// ---------------- graph build (atomic-free, 3 passes) ----------------

__global__ void __launch_bounds__(256) k_hist(const int* __restrict__ ei, int E, int chunk,
                                              int NW, unsigned* __restrict__ partialS,
                                              unsigned* __restrict__ partialD) {
    __shared__ unsigned lS[NWMAX];
    __shared__ unsigned lD[NWMAX];
    for (int w = threadIdx.x; w < NW; w += 256) { lS[w] = 0u; lD[w] = 0u; }
    __syncthreads();
    int e0 = blockIdx.x * chunk;
    int e1 = e0 + chunk; if (e1 > E) e1 = E;
    for (int e = e0 + threadIdx.x; e < e1; e += 256) {
        int s = ei[e], d = ei[E + e];
        atomicAdd(&lS[s >> 2], 1u << ((s & 3) * 8));
        atomicAdd(&lD[d >> 2], 1u << ((d & 3) * 8));
    }
    __syncthreads();
    unsigned* pS = partialS + (size_t)blockIdx.x * NW;
    unsigned* pD = partialD + (size_t)blockIdx.x * NW;
    for (int w = threadIdx.x; w < NW; w += 256) { pS[w] = lS[w]; pD[w] = lD[w]; }
}

__global__ void __launch_bounds__(256) k_red(const unsigned* __restrict__ partialS,
                                             const unsigned* __restrict__ partialD,
                                             unsigned* __restrict__ baseM, int NW, int n,
                                             float* __restrict__ dis,
                                             unsigned* __restrict__ cnt) {
    int w = blockIdx.x * 256 + threadIdx.x;
    if (w >= NW) return;
    unsigned s0 = 0, s1 = 0, s2 = 0, s3 = 0;
    unsigned c0 = 0, c1 = 0, c2 = 0, c3 = 0;
#pragma unroll 8
    for (int b = 0; b < NB; b++) {
        unsigned vs = partialS[(size_t)b * NW + w];
        unsigned vd = partialD[(size_t)b * NW + w];
        baseM[(size_t)b * NW + w] = c0 | (c1 << 8) | (c2 << 16) | (c3 << 24);
        s0 += vs & 0xFF; s1 += (vs >> 8) & 0xFF; s2 += (vs >> 16) & 0xFF; s3 += vs >> 24;
        c0 += vd & 0xFF; c1 += (vd >> 8) & 0xFF; c2 += (vd >> 16) & 0xFF; c3 += vd >> 24;
    }
    int node = w * 4;
    if (node + 3 < n) {
        ((float4*)dis)[w] = make_float4(s0 ? 1.0f / sqrtf((float)s0) : 0.0f,
                                        s1 ? 1.0f / sqrtf((float)s1) : 0.0f,
                                        s2 ? 1.0f / sqrtf((float)s2) : 0.0f,
                                        s3 ? 1.0f / sqrtf((float)s3) : 0.0f);
        ((uint4*)cnt)[w] = make_uint4(c0, c1, c2, c3);
    } else {
        unsigned ss[4] = {s0, s1, s2, s3}, cc[4] = {c0, c1, c2, c3};
        for (int j = 0; j < 4 && node + j < n; j++) {
            dis[node + j] = ss[j] ? 1.0f / sqrtf((float)ss[j]) : 0.0f;
            cnt[node + j] = cc[j];
        }
    }
}

__global__ void __launch_bounds__(256) k_scat(const int* __restrict__ ei, int E, int chunk,
                                              int NW, const unsigned* __restrict__ baseM,
                                              int* __restrict__ slot, int CAP) {
    __shared__ unsigned cur[NWMAX];
    __shared__ unsigned bs[NWMAX];
    const unsigned* bRow = baseM + (size_t)blockIdx.x * NW;
    for (int w = threadIdx.x; w < NW; w += 256) { cur[w] = 0u; bs[w] = bRow[w]; }
    __syncthreads();
    int e0 = blockIdx.x * chunk;
    int e1 = e0 + chunk; if (e1 > E) e1 = E;
    for (int e = e0 + threadIdx.x; e < e1; e += 256) {
        int s = ei[e], d = ei[E + e];
        int w = d >> 2, sh = (d & 3) * 8;
        unsigned rank = (atomicAdd(&cur[w], 1u << sh) >> sh) & 0xFF;
        unsigned pos = ((bs[w] >> sh) & 0xFF) + rank;
        if (pos < (unsigned)CAP) slot[(size_t)d * CAP + pos] = s;
    }
}

// ---------------- feature kernels ----------------

__global__ void k_cvt(const float* __restrict__ x, const float* __restrict__ dis,
                      uint2* __restrict__ g, int n) {
    int i = blockIdx.x * 256 + threadIdx.x;
    if (i >= n * 16) return;
    int node = i >> 4, fp = i & 15;
    float s = dis[node];
    float4 v = ((const float4*)x)[(size_t)node * 16 + fp];
    g[i] = make_uint2(pack2(s * v.x, s * v.y), pack2(s * v.z, s * v.w));
}

// out[d][:] = -dis[d] * sum_{e:dst=d} gsrc[src_e][:]   (gsrc bf16 = dis*h)
template <bool WG>
__global__ void __launch_bounds__(256) k_prop(const uint2* __restrict__ gsrc,
                                              const unsigned* __restrict__ cnt,
                                              const int* __restrict__ slot,
                                              const float* __restrict__ dis,
                                              float* __restrict__ out,
                                              uint2* __restrict__ gout, int n, int CAP) {
    int lane = threadIdx.x & 63;
    int node = (blockIdx.x << 2) + (threadIdx.x >> 6);
    if (node >= n) return;
    const int g = lane >> 4;
    const int fp = lane & 15;

    int m = (int)cnt[node];
    if (m > CAP) m = CAP;
    const int* __restrict__ base = slot + (size_t)node * CAP;

    float ax = 0.0f, ay = 0.0f, az = 0.0f, aw = 0.0f;
    int e = 0;
    for (; e + 8 <= m; e += 8) {
        int s0 = base[e + g];
        int s1 = base[e + 4 + g];
        uint2 q0 = gsrc[(size_t)s0 * 16 + fp];
        uint2 q1 = gsrc[(size_t)s1 * 16 + fp];
        ax += ubf_lo(q0.x); ay += ubf_hi(q0.x);
        az += ubf_lo(q0.y); aw += ubf_hi(q0.y);
        ax += ubf_lo(q1.x); ay += ubf_hi(q1.x);
        az += ubf_lo(q1.y); aw += ubf_hi(q1.y);
    }
    for (; e < m; e += 4) {
        int idx = e + g;
        bool valid = idx < m;
        int s0 = base[valid ? idx : e];
        unsigned msk = valid ? 0xFFFFFFFFu : 0u;
        uint2 q = gsrc[(size_t)s0 * 16 + fp];
        q.x &= msk; q.y &= msk;
        ax += ubf_lo(q.x); ay += ubf_hi(q.x);
        az += ubf_lo(q.y); aw += ubf_hi(q.y);
    }
    ax += __shfl_xor(ax, 16); ay += __shfl_xor(ay, 16);
    az += __shfl_xor(az, 16); aw += __shfl_xor(aw, 16);
    ax += __shfl_xor(ax, 32); ay += __shfl_xor(ay, 32);
    az += __shfl_xor(az, 32); aw += __shfl_xor(aw, 32);
    if (g == 0) {
        float s = dis[node];
        float fx = -s * ax, fy = -s * ay, fz = -s * az, fw = -s * aw;
        ((float4*)out)[(size_t)node * 16 + fp] = make_float4(fx, fy, fz, fw);
        if (WG)
            gout[(size_t)node * 16 + fp] =
                make_uint2(pack2(s * fx, s * fy), pack2(s * fz, s * fw));
    }
}

// combined per-layer weights: rows [0,64): W0-W2 ; [64,128): W1 ; [128,192): 2*W2
__global__ void k_wc(const float* __restrict__ W1, const float* __restrict__ W2,
                     const float* __restrict__ W3, float* __restrict__ WcAll) {
    int idx = blockIdx.x * 256 + threadIdx.x;
    const float* W;
    float* Wc;
    int outc;
    if (idx < 192 * 64) {
        W = W1; Wc = WcAll; outc = 64;
    } else if (idx < 2 * 192 * 64) {
        idx -= 192 * 64;
        W = W2; Wc = WcAll + 192 * 64; outc = 64;
    } else if (idx < 2 * 192 * 64 + 192 * 32) {
        idx -= 2 * 192 * 64;
        W = W3; Wc = WcAll + 2 * 192 * 64; outc = 32;
    } else {
        return;
    }
    int j = idx / outc, c = idx - j * outc;
    int seg = j >> 6, r = j & 63;
    float v;
    if (seg == 0)      v = W[r * outc + c] - W[(128 + r) * outc + c];
    else if (seg == 1) v = W[(64 + r) * outc + c];
    else               v = 2.0f * W[(128 + r) * outc + c];
    Wc[idx] = v;
}

// GEMM: thread = 4 nodes x CPT cols; block = 128 threads = 128 nodes.
// Round-8 profile: old 1-node/thread version was DS-throughput bound (16
// ds_read_b128 per k4 feeding only 64 FMA; ~110K cyc/CU = the whole 41 us).
// 4 nodes/thread amortizes the same 16 DS reads over 256 FMAs.
// k4 loop NOT unrolled (rounds 0-1: full unroll -> 256 VGPR + 1 GB spill).
template <int OUTC, bool RELU, bool WG>
__global__ void __launch_bounds__(128) k_gemm(const float* __restrict__ X0,
                                              const float* __restrict__ X1,
                                              const float* __restrict__ X2,
                                              const float* __restrict__ Wc,
                                              const float* __restrict__ bias,
                                              const float* __restrict__ dis,
                                              float* __restrict__ out,
                                              unsigned* __restrict__ gout, int n) {
    constexpr int CPT = OUTC / 4;   // 16 (layers 1,2) or 8 (layer 3)
    __shared__ float Wl[192 * OUTC];
    for (int i = threadIdx.x * 4; i < 192 * OUTC; i += 512) {
        *(float4*)&Wl[i] = *(const float4*)&Wc[i];
    }
    __syncthreads();

    const int group = threadIdx.x >> 2;       // 0..31
    const int c0 = (threadIdx.x & 3) * CPT;
    const int node0 = blockIdx.x * 128 + group * 4;
    if (node0 >= n) return;
    const int l0 = node0 < n ? node0 : n - 1;
    const int l1 = node0 + 1 < n ? node0 + 1 : n - 1;
    const int l2 = node0 + 2 < n ? node0 + 2 : n - 1;
    const int l3 = node0 + 3 < n ? node0 + 3 : n - 1;

    float acc[4][CPT];
#pragma unroll
    for (int c = 0; c < CPT; c++) {
        float bv = bias[c0 + c];
        acc[0][c] = bv; acc[1][c] = bv; acc[2][c] = bv; acc[3][c] = bv;
    }

#define SEG(Xp, soff)                                                         \
    do {                                                                      \
        const float* xr0 = (Xp) + (size_t)l0 * 64;                            \
        const float* xr1 = (Xp) + (size_t)l1 * 64;                            \
        const float* xr2 = (Xp) + (size_t)l2 * 64;                            \
        const float* xr3 = (Xp) + (size_t)l3 * 64;                            \
        const float* wseg = &Wl[(soff)*64 * OUTC] + c0;                       \
        _Pragma("unroll 1") for (int k4 = 0; k4 < 16; k4++) {                 \
            float4 a0 = *(const float4*)(xr0 + 4 * k4);                       \
            float4 a1 = *(const float4*)(xr1 + 4 * k4);                       \
            float4 a2 = *(const float4*)(xr2 + 4 * k4);                       \
            float4 a3 = *(const float4*)(xr3 + 4 * k4);                       \
            const float* w = wseg + (4 * k4) * OUTC;                          \
            _Pragma("unroll") for (int j = 0; j < CPT / 4; j++) {             \
                float4 w0v = *(const float4*)(w + 4 * j);                     \
                float4 w1v = *(const float4*)(w + OUTC + 4 * j);              \
                float4 w2v = *(const float4*)(w + 2 * OUTC + 4 * j);          \
                float4 w3v = *(const float4*)(w + 3 * OUTC + 4 * j);          \
                acc[0][4*j+0] = fmaf(a0.x, w0v.x, acc[0][4*j+0]);             \
                acc[0][4*j+1] = fmaf(a0.x, w0v.y, acc[0][4*j+1]);             \
                acc[0][4*j+2] = fmaf(a0.x, w0v.z, acc[0][4*j+2]);             \
                acc[0][4*j+3] = fmaf(a0.x, w0v.w, acc[0][4*j+3]);             \
                acc[0][4*j+0] = fmaf(a0.y, w1v.x, acc[0][4*j+0]);             \
                acc[0][4*j+1] = fmaf(a0.y, w1v.y, acc[0][4*j+1]);             \
                acc[0][4*j+2] = fmaf(a0.y, w1v.z, acc[0][4*j+2]);             \
                acc[0][4*j+3] = fmaf(a0.y, w1v.w, acc[0][4*j+3]);             \
                acc[0][4*j+0] = fmaf(a0.z, w2v.x, acc[0][4*j+0]);             \
                acc[0][4*j+1] = fmaf(a0.z, w2v.y, acc[0][4*j+1]);             \
                acc[0][4*j+2] = fmaf(a0.z, w2v.z, acc[0][4*j+2]);             \
                acc[0][4*j+3] = fmaf(a0.z, w2v.w, acc[0][4*j+3]);             \
                acc[0][4*j+0] = fmaf(a0.w, w3v.x, acc[0][4*j+0]);             \
                acc[0][4*j+1] = fmaf(a0.w, w3v.y, acc[0][4*j+1]);             \
                acc[0][4*j+2] = fmaf(a0.w, w3v.z, acc[0][4*j+2]);             \
                acc[0][4*j+3] = fmaf(a0.w, w3v.w, acc[0][4*j+3]);             \
                acc[1][4*j+0] = fmaf(a1.x, w0v.x, acc[1][4*j+0]);             \
                acc[1][4*j+1] = fmaf(a1.x, w0v.y, acc[1][4*j+1]);             \
                acc[1][4*j+2] = fmaf(a1.x, w0v.z, acc[1][4*j+2]);             \
                acc[1][4*j+3] = fmaf(a1.x, w0v.w, acc[1][4*j+3]);             \
                acc[1][4*j+0] = fmaf(a1.y, w1v.x, acc[1][4*j+0]);             \
                acc[1][4*j+1] = fmaf(a1.y, w1v.y, acc[1][4*j+1]);             \
                acc[1][4*j+2] = fmaf(a1.y, w1v.z, acc[1][4*j+2]);             \
                acc[1][4*j+3] = fmaf(a1.y, w1v.w, acc[1][4*j+3]);             \
                acc[1][4*j+0] = fmaf(a1.z, w2v.x, acc[1][4*j+0]);             \
                acc[1][4*j+1] = fmaf(a1.z, w2v.y, acc[1][4*j+1]);             \
                acc[1][4*j+2] = fmaf(a1.z, w2v.z, acc[1][4*j+2]);             \
                acc[1][4*j+3] = fmaf(a1.z, w2v.w, acc[1][4*j+3]);             \
                acc[1][4*j+0] = fmaf(a1.w, w3v.x, acc[1][4*j+0]);             \
                acc[1][4*j+1] = fmaf(a1.w, w3v.y, acc[1][4*j+1]);             \
                acc[1][4*j+2] = fmaf(a1.w, w3v.z, acc[1][4*j+2]);             \
                acc[1][4*j+3] = fmaf(a1.w, w3v.w, acc[1][4*j+3]);             \
                acc[2][4*j+0] = fmaf(a2.x, w0v.x, acc[2][4*j+0]);             \
                acc[2][4*j+1] = fmaf(a2.x, w0v.y, acc[2][4*j+1]);             \
                acc[2][4*j+2] = fmaf(a2.x, w0v.z, acc[2][4*j+2]);             \
                acc[2][4*j+3] = fmaf(a2.x, w0v.w, acc[2][4*j+3]);             \
                acc[2][4*j+0] = fmaf(a2.y, w1v.x, acc[2][4*j+0]);             \
                acc[2][4*j+1] = fmaf(a2.y, w1v.y, acc[2][4*j+1]);             \
                acc[2][4*j+2] = fmaf(a2.y, w1v.z, acc[2][4*j+2]);             \
                acc[2][4*j+3] = fmaf(a2.y, w1v.w, acc[2][4*j+3]);             \
                acc[2][4*j+0] = fmaf(a2.z, w2v.x, acc[2][4*j+0]);             \
                acc[2][4*j+1] = fmaf(a2.z, w2v.y, acc[2][4*j+1]);             \
                acc[2][4*j+2] = fmaf(a2.z, w2v.z, acc[2][4*j+2]);             \
                acc[2][4*j+3] = fmaf(a2.z, w2v.w, acc[2][4*j+3]);             \
                acc[2][4*j+0] = fmaf(a2.w, w3v.x, acc[2][4*j+0]);             \
                acc[2][4*j+1] = fmaf(a2.w, w3v.y, acc[2][4*j+1]);             \
                acc[2][4*j+2] = fmaf(a2.w, w3v.z, acc[2][4*j+2]);             \
                acc[2][4*j+3] = fmaf(a2.w, w3v.w, acc[2][4*j+3]);             \
                acc[3][4*j+0] = fmaf(a3.x, w0v.x, acc[3][4*j+0]);             \
                acc[3][4*j+1] = fmaf(a3.x, w0v.y, acc[3][4*j+1]);             \
                acc[3][4*j+2] = fmaf(a3.x, w0v.z, acc[3][4*j+2]);             \
                acc[3][4*j+3] = fmaf(a3.x, w0v.w, acc[3][4*j+3]);             \
                acc[3][4*j+0] = fmaf(a3.y, w1v.x, acc[3][4*j+0]);             \
                acc[3][4*j+1] = fmaf(a3.y, w1v.y, acc[3][4*j+1]);             \
                acc[3][4*j+2] = fmaf(a3.y, w1v.z, acc[3][4*j+2]);             \
                acc[3][4*j+3] = fmaf(a3.y, w1v.w, acc[3][4*j+3]);             \
                acc[3][4*j+0] = fmaf(a3.z, w2v.x, acc[3][4*j+0]);             \
                acc[3][4*j+1] = fmaf(a3.z, w2v.y, acc[3][4*j+1]);             \
                acc[3][4*j+2] = fmaf(a3.z, w2v.z, acc[3][4*j+2]);             \
                acc[3][4*j+3] = fmaf(a3.z, w2v.w, acc[3][4*j+3]);             \
                acc[3][4*j+0] = fmaf(a3.w, w3v.x, acc[3][4*j+0]);             \
                acc[3][4*j+1] = fmaf(a3.w, w3v.y, acc[3][4*j+1]);             \
                acc[3][4*j+2] = fmaf(a3.w, w3v.z, acc[3][4*j+2]);             \
                acc[3][4*j+3] = fmaf(a3.w, w3v.w, acc[3][4*j+3]);             \
            }                                                                 \
        }                                                                     \
    } while (0)

    SEG(X0, 0);
    SEG(X1, 1);
    SEG(X2, 2);
#undef SEG

#pragma unroll
    for (int ni = 0; ni < 4; ni++) {
        int node = node0 + ni;
        if (node >= n) break;
        if (RELU) {
#pragma unroll
            for (int c = 0; c < CPT; c++) acc[ni][c] = fmaxf(acc[ni][c], 0.0f);
        }
        float* o = out + (size_t)node * OUTC + c0;
#pragma unroll
        for (int j = 0; j < CPT / 4; j++) {
            *(float4*)(o + 4 * j) = make_float4(acc[ni][4 * j + 0], acc[ni][4 * j + 1],
                                                acc[ni][4 * j + 2], acc[ni][4 * j + 3]);
        }
        if (WG) {
            float s = dis[node];
            unsigned* gr = gout + (size_t)node * (OUTC / 2) + c0 / 2;
#pragma unroll
            for (int j = 0; j < CPT / 8; j++) {
                uint4 pk;
                pk.x = pack2(s * acc[ni][8 * j + 0], s * acc[ni][8 * j + 1]);
                pk.y = pack2(s * acc[ni][8 * j + 2], s * acc[ni][8 * j + 3]);
                pk.z = pack2(s * acc[ni][8 * j + 4], s * acc[ni][8 * j + 5]);
                pk.w = pack2(s * acc[ni][8 * j + 6], s * acc[ni][8 * j + 7]);
                *(uint4*)(gr + 4 * j) = pk;
            }
        }
    }
}

// ---------------- launcher ----------------

extern "C" void kernel_launch(void* const* d_in, const int* in_sizes, int n_in,
                              void* d_out, int out_size, void* d_ws, size_t ws_size,
                              hipStream_t stream) {
    const float* x  = (const float*)d_in[0];
    const int*   ei = (const int*)d_in[1];
    const float* W1 = (const float*)d_in[2];
    const float* b1 = (const float*)d_in[3];
    const float* W2 = (const float*)d_in[4];
    const float* b2 = (const float*)d_in[5];
    const float* W3 = (const float*)d_in[6];
    const float* b3 = (const float*)d_in[7];
    float* out = (float*)d_out;

    const int n = in_sizes[0] / 64;
    const int E = in_sizes[1] / 2;
    const int NW = (n + 3) >> 2;
    const int chunk = (E + NB - 1) / NB;

    char* wsp = (char*)d_ws;
    size_t off = 0;
    auto alloc = [&](size_t bytes) -> char* {
        char* p = wsp + off;
        off += (bytes + 255) & ~(size_t)255;
        return p;
    };
    float* dis     = (float*)alloc((size_t)n * 4);
    unsigned* cnt  = (unsigned*)alloc((size_t)n * 4);
    float* bufs    = (float*)alloc((size_t)4 * n * 64 * 4 + 4096);  // A|B|C|D
    float* A = bufs, *B = A + (size_t)n * 64, *C = B + (size_t)n * 64, *D = C + (size_t)n * 64;
    float* WcAll   = (float*)alloc((size_t)(2 * 192 * 64 + 192 * 32) * 4);
    uint2* g0      = (uint2*)alloc((size_t)n * 64 * 2);
    uint2* g1      = (uint2*)alloc((size_t)n * 64 * 2);

    // build temporaries alias A..C (dead before first prop writes A)
    unsigned* partialS = (unsigned*)bufs;
    unsigned* partialD = partialS + (size_t)NB * NW;
    unsigned* baseM    = partialD + (size_t)NB * NW;

    size_t leftover = (ws_size > off) ? (ws_size - off) : 0;
    int CAP = (int)(leftover / ((size_t)n * 4));
    if (CAP > 64) CAP = 64;
    if (CAP < 16) CAP = 16;
    int* slot = (int*)alloc((size_t)n * CAP * 4);

    const int nb_cvt  = (n * 16 + 255) / 256;
    const int nb_red  = (NW + 255) / 256;
    const int nb_prop = (n + 3) / 4;
    const int nb_gemm = (n + 127) / 128;
    const int nb_wc   = (2 * 192 * 64 + 192 * 32 + 255) / 256;

    k_hist<<<NB, 256, 0, stream>>>(ei, E, chunk, NW, partialS, partialD);
    k_red<<<nb_red, 256, 0, stream>>>(partialS, partialD, baseM, NW, n, dis, cnt);
    k_scat<<<NB, 256, 0, stream>>>(ei, E, chunk, NW, baseM, slot, CAP);
    k_cvt<<<nb_cvt, 256, 0, stream>>>(x, dis, g0, n);
    k_wc<<<nb_wc, 256, 0, stream>>>(W1, W2, W3, WcAll);

    // layer 1: x -> C
    k_prop<true><<<nb_prop, 256, 0, stream>>>(g0, cnt, slot, dis, A, g1, n, CAP);
    k_prop<false><<<nb_prop, 256, 0, stream>>>(g1, cnt, slot, dis, B, nullptr, n, CAP);
    k_gemm<64, true, true><<<nb_gemm, 128, 0, stream>>>(x, A, B, WcAll, b1, dis, C,
                                                        (unsigned*)g0, n);

    // layer 2: C -> D
    k_prop<true><<<nb_prop, 256, 0, stream>>>(g0, cnt, slot, dis, A, g1, n, CAP);
    k_prop<false><<<nb_prop, 256, 0, stream>>>(g1, cnt, slot, dis, B, nullptr, n, CAP);
    k_gemm<64, true, true><<<nb_gemm, 128, 0, stream>>>(C, A, B, WcAll + 192 * 64, b2, dis,
                                                        D, (unsigned*)g0, n);

    // layer 3: D -> out (32 cols, no relu)
    k_prop<true><<<nb_prop, 256, 0, stream>>>(g0, cnt, slot, dis, A, g1, n, CAP);
    k_prop<false><<<nb_prop, 256, 0, stream>>>(g1, cnt, slot, dis, B, nullptr, n, CAP);
    k_gemm<32, false, false><<<nb_gemm, 128, 0, stream>>>(D, A, B, WcAll + 2 * 192 * 64, b3,
                                                          dis, out, nullptr, n);
}

// Round 10
// 246.089 us; speedup vs baseline: 1.3272x; 1.3272x over previous
//
#include <hip/hip_runtime.h>

#define NB 256        // partition blocks (1 per CU)
#define NWMAX 16384   // max packed words (n <= 65532); n=50000 -> NW=12500

typedef __attribute__((ext_vector_type(8))) short bf16x8;
typedef __attribute__((ext_vector_type(4))) float f32x4;

// bf16 round-to-nearest-even helpers
__device__ __forceinline__ unsigned bfr(float x) {
    unsigned u = __float_as_uint(x);
    return (u + 0x7FFFu + ((u >> 16) & 1u)) >> 16;
}
__device__ __forceinline__ unsigned pack2(float lo, float hi) {
    return bfr(lo) | (bfr(hi) << 16);
}
__device__ __forceinline__ float ubf_lo(unsigned q) { return __uint_as_float(q << 16); }
__device__ __forceinline__ float ubf_hi(unsigned q) { return __uint_as_float(q & 0xFFFF0000u); }

// ---------------- graph build (atomic-free, 3 passes; unchanged r8) ----------------

__global__ void __launch_bounds__(256) k_hist(const int* __restrict__ ei, int E, int chunk,
                                              int NW, unsigned* __restrict__ partialS,
                                              unsigned* __restrict__ partialD) {
    __shared__ unsigned lS[NWMAX];
    __shared__ unsigned lD[NWMAX];
    for (int w = threadIdx.x; w < NW; w += 256) { lS[w] = 0u; lD[w] = 0u; }
    __syncthreads();
    int e0 = blockIdx.x * chunk;
    int e1 = e0 + chunk; if (e1 > E) e1 = E;
    for (int e = e0 + threadIdx.x; e < e1; e += 256) {
        int s = ei[e], d = ei[E + e];
        atomicAdd(&lS[s >> 2], 1u << ((s & 3) * 8));
        atomicAdd(&lD[d >> 2], 1u << ((d & 3) * 8));
    }
    __syncthreads();
    unsigned* pS = partialS + (size_t)blockIdx.x * NW;
    unsigned* pD = partialD + (size_t)blockIdx.x * NW;
    for (int w = threadIdx.x; w < NW; w += 256) { pS[w] = lS[w]; pD[w] = lD[w]; }
}

__global__ void __launch_bounds__(256) k_red(const unsigned* __restrict__ partialS,
                                             const unsigned* __restrict__ partialD,
                                             unsigned* __restrict__ baseM, int NW, int n,
                                             float* __restrict__ dis,
                                             unsigned* __restrict__ cnt) {
    int w = blockIdx.x * 256 + threadIdx.x;
    if (w >= NW) return;
    unsigned s0 = 0, s1 = 0, s2 = 0, s3 = 0;
    unsigned c0 = 0, c1 = 0, c2 = 0, c3 = 0;
#pragma unroll 8
    for (int b = 0; b < NB; b++) {
        unsigned vs = partialS[(size_t)b * NW + w];
        unsigned vd = partialD[(size_t)b * NW + w];
        baseM[(size_t)b * NW + w] = c0 | (c1 << 8) | (c2 << 16) | (c3 << 24);
        s0 += vs & 0xFF; s1 += (vs >> 8) & 0xFF; s2 += (vs >> 16) & 0xFF; s3 += vs >> 24;
        c0 += vd & 0xFF; c1 += (vd >> 8) & 0xFF; c2 += (vd >> 16) & 0xFF; c3 += vd >> 24;
    }
    int node = w * 4;
    if (node + 3 < n) {
        ((float4*)dis)[w] = make_float4(s0 ? 1.0f / sqrtf((float)s0) : 0.0f,
                                        s1 ? 1.0f / sqrtf((float)s1) : 0.0f,
                                        s2 ? 1.0f / sqrtf((float)s2) : 0.0f,
                                        s3 ? 1.0f / sqrtf((float)s3) : 0.0f);
        ((uint4*)cnt)[w] = make_uint4(c0, c1, c2, c3);
    } else {
        unsigned ss[4] = {s0, s1, s2, s3}, cc[4] = {c0, c1, c2, c3};
        for (int j = 0; j < 4 && node + j < n; j++) {
            dis[node + j] = ss[j] ? 1.0f / sqrtf((float)ss[j]) : 0.0f;
            cnt[node + j] = cc[j];
        }
    }
}

__global__ void __launch_bounds__(256) k_scat(const int* __restrict__ ei, int E, int chunk,
                                              int NW, const unsigned* __restrict__ baseM,
                                              int* __restrict__ slot, int CAP) {
    __shared__ unsigned cur[NWMAX];
    __shared__ unsigned bs[NWMAX];
    const unsigned* bRow = baseM + (size_t)blockIdx.x * NW;
    for (int w = threadIdx.x; w < NW; w += 256) { cur[w] = 0u; bs[w] = bRow[w]; }
    __syncthreads();
    int e0 = blockIdx.x * chunk;
    int e1 = e0 + chunk; if (e1 > E) e1 = E;
    for (int e = e0 + threadIdx.x; e < e1; e += 256) {
        int s = ei[e], d = ei[E + e];
        int w = d >> 2, sh = (d & 3) * 8;
        unsigned rank = (atomicAdd(&cur[w], 1u << sh) >> sh) & 0xFF;
        unsigned pos = ((bs[w] >> sh) & 0xFF) + rank;
        if (pos < (unsigned)CAP) slot[(size_t)d * CAP + pos] = s;
    }
}

// ---------------- feature kernels ----------------

// xb0 = bf16(x); g0 = bf16(dis ⊙ x)
__global__ void k_cvt(const float* __restrict__ x, const float* __restrict__ dis,
                      uint2* __restrict__ g, uint2* __restrict__ xb, int n) {
    int i = blockIdx.x * 256 + threadIdx.x;
    if (i >= n * 16) return;
    int node = i >> 4;
    float s = dis[node];
    float4 v = ((const float4*)x)[i];
    xb[i] = make_uint2(pack2(v.x, v.y), pack2(v.z, v.w));
    g[i]  = make_uint2(pack2(s * v.x, s * v.y), pack2(s * v.z, s * v.w));
}

// out[d][:] = -dis[d] * sum_{e:dst=d} gsrc[src_e][:]  -> bf16 xbout (+ optional bf16 gout)
template <bool WG>
__global__ void __launch_bounds__(256) k_prop(const uint2* __restrict__ gsrc,
                                              const unsigned* __restrict__ cnt,
                                              const int* __restrict__ slot,
                                              const float* __restrict__ dis,
                                              uint2* __restrict__ xbout,
                                              uint2* __restrict__ gout, int n, int CAP) {
    int lane = threadIdx.x & 63;
    int node = (blockIdx.x << 2) + (threadIdx.x >> 6);
    if (node >= n) return;
    const int g = lane >> 4;
    const int fp = lane & 15;

    int m = (int)cnt[node];
    if (m > CAP) m = CAP;
    const int* __restrict__ base = slot + (size_t)node * CAP;

    float ax = 0.0f, ay = 0.0f, az = 0.0f, aw = 0.0f;
    int e = 0;
    for (; e + 8 <= m; e += 8) {
        int s0 = base[e + g];
        int s1 = base[e + 4 + g];
        uint2 q0 = gsrc[(size_t)s0 * 16 + fp];
        uint2 q1 = gsrc[(size_t)s1 * 16 + fp];
        ax += ubf_lo(q0.x); ay += ubf_hi(q0.x);
        az += ubf_lo(q0.y); aw += ubf_hi(q0.y);
        ax += ubf_lo(q1.x); ay += ubf_hi(q1.x);
        az += ubf_lo(q1.y); aw += ubf_hi(q1.y);
    }
    for (; e < m; e += 4) {
        int idx = e + g;
        bool valid = idx < m;
        int s0 = base[valid ? idx : e];
        unsigned msk = valid ? 0xFFFFFFFFu : 0u;
        uint2 q = gsrc[(size_t)s0 * 16 + fp];
        q.x &= msk; q.y &= msk;
        ax += ubf_lo(q.x); ay += ubf_hi(q.x);
        az += ubf_lo(q.y); aw += ubf_hi(q.y);
    }
    ax += __shfl_xor(ax, 16); ay += __shfl_xor(ay, 16);
    az += __shfl_xor(az, 16); aw += __shfl_xor(aw, 16);
    ax += __shfl_xor(ax, 32); ay += __shfl_xor(ay, 32);
    az += __shfl_xor(az, 32); aw += __shfl_xor(aw, 32);
    if (g == 0) {
        float s = dis[node];
        float fx = -s * ax, fy = -s * ay, fz = -s * az, fw = -s * aw;
        xbout[(size_t)node * 16 + fp] = make_uint2(pack2(fx, fy), pack2(fz, fw));
        if (WG)
            gout[(size_t)node * 16 + fp] =
                make_uint2(pack2(s * fx, s * fy), pack2(s * fz, s * fw));
    }
}

// Pre-swizzled bf16 B-fragments of the combined weights.
// Layer layout: frag f = ks*NCT + ct (ks = K-step of 32, ct = 16-col tile);
// element ((f*64 + lane)*8 + j) = Wcomb[k = ks*32 + (lane>>4)*8 + j][col = ct*16 + (lane&15)]
// Wcomb rows: [0,64): W0-W2 ; [64,128): W1 ; [128,192): 2*W2.
__global__ void k_wb(const float* __restrict__ W1, const float* __restrict__ W2,
                     const float* __restrict__ W3, ushort* __restrict__ Wb) {
    int idx = blockIdx.x * 256 + threadIdx.x;   // one thread per (frag, lane)
    if (idx >= (24 + 24 + 12) * 64) return;
    const float* W; int OUTC, NCT, f; ushort* dst;
    if (idx < 24 * 64)      { W = W1; OUTC = 64; NCT = 4; dst = Wb;              f = idx >> 6; }
    else if (idx < 48 * 64) { W = W2; OUTC = 64; NCT = 4; dst = Wb + 24 * 512;   f = (idx >> 6) - 24; }
    else                    { W = W3; OUTC = 32; NCT = 2; dst = Wb + 48 * 512;   f = (idx >> 6) - 48; }
    int l = idx & 63;
    int ks = f / NCT, ct = f - ks * NCT;
    int col = ct * 16 + (l & 15);
    int k0 = ks * 32 + (l >> 4) * 8;
    unsigned pk[4];
    for (int jj = 0; jj < 4; jj++) {
        unsigned lohi[2];
        for (int h = 0; h < 2; h++) {
            int k = k0 + jj * 2 + h;
            int seg = k >> 6, r = k & 63;
            float v;
            if (seg == 0)      v = W[r * OUTC + col] - W[(128 + r) * OUTC + col];
            else if (seg == 1) v = W[(64 + r) * OUTC + col];
            else               v = 2.0f * W[(128 + r) * OUTC + col];
            lohi[h] = bfr(v);
        }
        pk[jj] = lohi[0] | (lohi[1] << 16);
    }
    *(uint4*)(dst + ((size_t)f * 64 + l) * 8) = make_uint4(pk[0], pk[1], pk[2], pk[3]);
}

// one 64-K segment (2 MFMA K-steps) of the MFMA GEMM
template <int NCT>
__device__ __forceinline__ void mm_seg(const ushort* __restrict__ Xp,
                                       const ushort* __restrict__ Wb, int ks0, int l,
                                       int rA0, int rA1, int koff, f32x4* c0, f32x4* c1) {
#pragma unroll
    for (int kt = 0; kt < 2; kt++) {
        bf16x8 a0 = *(const bf16x8*)(Xp + (size_t)rA0 * 64 + kt * 32 + koff);
        bf16x8 a1 = *(const bf16x8*)(Xp + (size_t)rA1 * 64 + kt * 32 + koff);
        int ks = ks0 + kt;
#pragma unroll
        for (int ct = 0; ct < NCT; ct++) {
            bf16x8 b = *(const bf16x8*)(Wb + ((size_t)(ks * NCT + ct) * 64 + l) * 8);
            c0[ct] = __builtin_amdgcn_mfma_f32_16x16x32_bf16(a0, b, c0[ct], 0, 0, 0);
            c1[ct] = __builtin_amdgcn_mfma_f32_16x16x32_bf16(a1, b, c1[ct], 0, 0, 0);
        }
    }
}

// MFMA GEMM: 1 wave/block, 32 rows x OUTC cols, K = 192 (3 bf16 segments).
// A-frag: lane l reads 8 contiguous bf16 at X[r + (l&15)][kt*32 + (l>>4)*8] (row-major ok).
// B-frag: pre-swizzled by k_wb -> one 16B load per frag.
// C/D layout (m89-verified): col = lane&15, row = (lane>>4)*4 + reg.
// Epilogue: RELU + bf16 xbout + bf16 gout (layers 1,2) or f32 out (layer 3).
template <int NCT, bool RELU, bool WG>
__global__ void __launch_bounds__(64, 4) k_mm(const ushort* __restrict__ X0,
                                              const ushort* __restrict__ X1,
                                              const ushort* __restrict__ X2,
                                              const ushort* __restrict__ Wb,
                                              const float* __restrict__ bias,
                                              const float* __restrict__ dis,
                                              float* __restrict__ outf,
                                              ushort* __restrict__ xbout,
                                              ushort* __restrict__ gout, int n) {
    constexpr int OUTC = NCT * 16;
    const int l = threadIdx.x & 63;
    const int r0 = blockIdx.x * 32;
    if (r0 >= n) return;
    const int lm = l & 15, lh = l >> 4;
    const int rA0 = (r0 + lm < n) ? r0 + lm : n - 1;
    const int rA1 = (r0 + 16 + lm < n) ? r0 + 16 + lm : n - 1;
    const int koff = lh * 8;

    f32x4 c0[NCT], c1[NCT];
#pragma unroll
    for (int ct = 0; ct < NCT; ct++) {
        float bv = bias[ct * 16 + lm];
        f32x4 cv = {bv, bv, bv, bv};
        c0[ct] = cv;
        c1[ct] = cv;
    }

    mm_seg<NCT>(X0, Wb, 0, l, rA0, rA1, koff, c0, c1);
    mm_seg<NCT>(X1, Wb, 2, l, rA0, rA1, koff, c0, c1);
    mm_seg<NCT>(X2, Wb, 4, l, rA0, rA1, koff, c0, c1);

#pragma unroll
    for (int half = 0; half < 2; half++) {
        int rbase = r0 + half * 16 + lh * 4;
#pragma unroll
        for (int ct = 0; ct < NCT; ct++) {
            int col = ct * 16 + lm;
#pragma unroll
            for (int r = 0; r < 4; r++) {
                int row = rbase + r;
                if (row < n) {
                    float v = half ? c1[ct][r] : c0[ct][r];
                    if (RELU) v = fmaxf(v, 0.0f);
                    if (WG) {
                        float s = dis[row];
                        xbout[(size_t)row * OUTC + col] = (ushort)bfr(v);
                        gout[(size_t)row * OUTC + col] = (ushort)bfr(s * v);
                    } else {
                        outf[(size_t)row * OUTC + col] = v;
                    }
                }
            }
        }
    }
}

// ---------------- launcher ----------------

extern "C" void kernel_launch(void* const* d_in, const int* in_sizes, int n_in,
                              void* d_out, int out_size, void* d_ws, size_t ws_size,
                              hipStream_t stream) {
    const float* x  = (const float*)d_in[0];
    const int*   ei = (const int*)d_in[1];
    const float* W1 = (const float*)d_in[2];
    const float* b1 = (const float*)d_in[3];
    const float* W2 = (const float*)d_in[4];
    const float* b2 = (const float*)d_in[5];
    const float* W3 = (const float*)d_in[6];
    const float* b3 = (const float*)d_in[7];
    float* out = (float*)d_out;

    const int n = in_sizes[0] / 64;
    const int E = in_sizes[1] / 2;
    const int NW = (n + 3) >> 2;
    const int chunk = (E + NB - 1) / NB;

    char* wsp = (char*)d_ws;
    size_t off = 0;
    auto alloc = [&](size_t bytes) -> char* {
        char* p = wsp + off;
        off += (bytes + 255) & ~(size_t)255;
        return p;
    };
    float* dis     = (float*)alloc((size_t)n * 4);
    unsigned* cnt  = (unsigned*)alloc((size_t)n * 4);
    const size_t XB = (size_t)n * 64 * 2;     // one bf16 feature buffer (multiple of 256)
    ushort* xb0 = (ushort*)alloc(XB);
    ushort* xbA = (ushort*)alloc(XB);
    ushort* xbB = (ushort*)alloc(XB);
    ushort* xbC = (ushort*)alloc(XB);
    ushort* xbD = (ushort*)alloc(XB);
    ushort* g0  = (ushort*)alloc(XB);
    ushort* g1  = (ushort*)alloc(XB);
    ushort* Wb  = (ushort*)alloc((size_t)60 * 512 * 2);

    // build temporaries alias bf16 buffers (dead before their writers run):
    // baseM (NB*NW*4 = 2n*64*2*... = 12.8MB) over xbA|xbB; partialS over xbC|xbD;
    // partialD over g0|g1. k_cvt/props run after k_scat.
    unsigned* baseM    = (unsigned*)xbA;
    unsigned* partialS = (unsigned*)xbC;
    unsigned* partialD = (unsigned*)g0;

    size_t leftover = (ws_size > off) ? (ws_size - off) : 0;
    int CAP = (int)(leftover / ((size_t)n * 4));
    if (CAP > 64) CAP = 64;
    if (CAP < 16) CAP = 16;
    int* slot = (int*)alloc((size_t)n * CAP * 4);

    const int nb_cvt  = (n * 16 + 255) / 256;
    const int nb_red  = (NW + 255) / 256;
    const int nb_prop = (n + 3) / 4;
    const int nb_mm   = (n + 31) / 32;
    const int nb_wb   = (60 * 64 + 255) / 256;

    k_hist<<<NB, 256, 0, stream>>>(ei, E, chunk, NW, partialS, partialD);
    k_red<<<nb_red, 256, 0, stream>>>(partialS, partialD, baseM, NW, n, dis, cnt);
    k_scat<<<NB, 256, 0, stream>>>(ei, E, chunk, NW, baseM, slot, CAP);
    k_cvt<<<nb_cvt, 256, 0, stream>>>(x, dis, (uint2*)g0, (uint2*)xb0, n);
    k_wb<<<nb_wb, 256, 0, stream>>>(W1, W2, W3, Wb);

    // layer 1
    k_prop<true><<<nb_prop, 256, 0, stream>>>((uint2*)g0, cnt, slot, dis, (uint2*)xbA,
                                              (uint2*)g1, n, CAP);
    k_prop<false><<<nb_prop, 256, 0, stream>>>((uint2*)g1, cnt, slot, dis, (uint2*)xbB,
                                               nullptr, n, CAP);
    k_mm<4, true, true><<<nb_mm, 64, 0, stream>>>(xb0, xbA, xbB, Wb, b1, dis, nullptr,
                                                  xbC, g0, n);

    // layer 2
    k_prop<true><<<nb_prop, 256, 0, stream>>>((uint2*)g0, cnt, slot, dis, (uint2*)xbA,
                                              (uint2*)g1, n, CAP);
    k_prop<false><<<nb_prop, 256, 0, stream>>>((uint2*)g1, cnt, slot, dis, (uint2*)xbB,
                                               nullptr, n, CAP);
    k_mm<4, true, true><<<nb_mm, 64, 0, stream>>>(xbC, xbA, xbB, Wb + 24 * 512, b2, dis,
                                                  nullptr, xbD, g0, n);

    // layer 3 (32 cols, no relu, f32 out)
    k_prop<true><<<nb_prop, 256, 0, stream>>>((uint2*)g0, cnt, slot, dis, (uint2*)xbA,
                                              (uint2*)g1, n, CAP);
    k_prop<false><<<nb_prop, 256, 0, stream>>>((uint2*)g1, cnt, slot, dis, (uint2*)xbB,
                                               nullptr, n, CAP);
    k_mm<2, false, false><<<nb_mm, 64, 0, stream>>>(xbD, xbA, xbB, Wb + 48 * 512, b3, dis,
                                                    out, nullptr, nullptr, n);
}

// Round 11
// 196.127 us; speedup vs baseline: 1.6653x; 1.2547x over previous
//
#include <hip/hip_runtime.h>

#define NB 128        // partition blocks for the graph build
#define NWMAX 16384   // max packed words (n <= 65532); n=50000 -> NW=12500

typedef __attribute__((ext_vector_type(8))) short bf16x8;
typedef __attribute__((ext_vector_type(4))) float f32x4;

// bf16 round-to-nearest-even helpers
__device__ __forceinline__ unsigned bfr(float x) {
    unsigned u = __float_as_uint(x);
    return (u + 0x7FFFu + ((u >> 16) & 1u)) >> 16;
}
__device__ __forceinline__ unsigned pack2(float lo, float hi) {
    return bfr(lo) | (bfr(hi) << 16);
}
__device__ __forceinline__ float ubf_lo(unsigned q) { return __uint_as_float(q << 16); }
__device__ __forceinline__ float ubf_hi(unsigned q) { return __uint_as_float(q & 0xFFFF0000u); }

// ---------------- graph build (atomic-free, 3 passes) ----------------

__global__ void __launch_bounds__(256) k_hist(const int* __restrict__ ei, int E, int chunk,
                                              int NW, unsigned* __restrict__ partialS,
                                              unsigned* __restrict__ partialD) {
    __shared__ unsigned lS[NWMAX];
    __shared__ unsigned lD[NWMAX];
    for (int w = threadIdx.x; w < NW; w += 256) { lS[w] = 0u; lD[w] = 0u; }
    __syncthreads();
    int e0 = blockIdx.x * chunk;
    int e1 = e0 + chunk; if (e1 > E) e1 = E;
    for (int e = e0 + threadIdx.x; e < e1; e += 256) {
        int s = ei[e], d = ei[E + e];
        atomicAdd(&lS[s >> 2], 1u << ((s & 3) * 8));
        atomicAdd(&lD[d >> 2], 1u << ((d & 3) * 8));
    }
    __syncthreads();
    unsigned* pS = partialS + (size_t)blockIdx.x * NW;
    unsigned* pD = partialD + (size_t)blockIdx.x * NW;
    for (int w = threadIdx.x; w < NW; w += 256) { pS[w] = lS[w]; pD[w] = lD[w]; }
}

// Per word (4 nodes): deg -> dis; cnt; per-block exclusive base bytes.
// Also writes the slot-list pad entries (src = n, the zero row) so k_prop
// needs no tail masking.
__global__ void __launch_bounds__(256) k_red(const unsigned* __restrict__ partialS,
                                             const unsigned* __restrict__ partialD,
                                             unsigned* __restrict__ baseM, int NW, int n,
                                             float* __restrict__ dis,
                                             unsigned* __restrict__ cnt,
                                             int* __restrict__ slot, int CAP) {
    int w = blockIdx.x * 256 + threadIdx.x;
    if (w >= NW) return;
    unsigned s0 = 0, s1 = 0, s2 = 0, s3 = 0;
    unsigned c0 = 0, c1 = 0, c2 = 0, c3 = 0;
#pragma unroll 8
    for (int b = 0; b < NB; b++) {
        unsigned vs = partialS[(size_t)b * NW + w];
        unsigned vd = partialD[(size_t)b * NW + w];
        baseM[(size_t)b * NW + w] = c0 | (c1 << 8) | (c2 << 16) | (c3 << 24);
        s0 += vs & 0xFF; s1 += (vs >> 8) & 0xFF; s2 += (vs >> 16) & 0xFF; s3 += vs >> 24;
        c0 += vd & 0xFF; c1 += (vd >> 8) & 0xFF; c2 += (vd >> 16) & 0xFF; c3 += vd >> 24;
    }
    unsigned ss[4] = {s0, s1, s2, s3}, cc[4] = {c0, c1, c2, c3};
    int node0 = w * 4;
    if (node0 + 3 < n) {
        ((float4*)dis)[w] = make_float4(s0 ? 1.0f / sqrtf((float)s0) : 0.0f,
                                        s1 ? 1.0f / sqrtf((float)s1) : 0.0f,
                                        s2 ? 1.0f / sqrtf((float)s2) : 0.0f,
                                        s3 ? 1.0f / sqrtf((float)s3) : 0.0f);
        ((uint4*)cnt)[w] = make_uint4(c0, c1, c2, c3);
    } else {
        for (int j = 0; j < 4 && node0 + j < n; j++) {
            dis[node0 + j] = ss[j] ? 1.0f / sqrtf((float)ss[j]) : 0.0f;
            cnt[node0 + j] = cc[j];
        }
    }
    // pad each node's slot list up to a multiple of 4 with src = n (zero row)
#pragma unroll
    for (int j = 0; j < 4; j++) {
        int node = node0 + j;
        if (node >= n) break;
        int c = (int)cc[j]; if (c > CAP) c = CAP;
        int c4 = (c + 3) & ~3; if (c4 > CAP) c4 = CAP;
        for (int e = c; e < c4; e++) slot[(size_t)node * CAP + e] = n;
    }
}

__global__ void __launch_bounds__(256) k_scat(const int* __restrict__ ei, int E, int chunk,
                                              int NW, const unsigned* __restrict__ baseM,
                                              int* __restrict__ slot, int CAP) {
    __shared__ unsigned cur[NWMAX];
    __shared__ unsigned bs[NWMAX];
    const unsigned* bRow = baseM + (size_t)blockIdx.x * NW;
    for (int w = threadIdx.x; w < NW; w += 256) { cur[w] = 0u; bs[w] = bRow[w]; }
    __syncthreads();
    int e0 = blockIdx.x * chunk;
    int e1 = e0 + chunk; if (e1 > E) e1 = E;
    for (int e = e0 + threadIdx.x; e < e1; e += 256) {
        int s = ei[e], d = ei[E + e];
        int w = d >> 2, sh = (d & 3) * 8;
        unsigned rank = (atomicAdd(&cur[w], 1u << sh) >> sh) & 0xFF;
        unsigned pos = ((bs[w] >> sh) & 0xFF) + rank;
        if (pos < (unsigned)CAP) slot[(size_t)d * CAP + pos] = s;
    }
}

// ---------------- setup: cvt (+ zero pad row) and W fragment swizzle, fused ----------------

__global__ void __launch_bounds__(256) k_setup(const float* __restrict__ x,
                                               const float* __restrict__ dis,
                                               uint2* __restrict__ g0,
                                               uint2* __restrict__ g1,
                                               uint2* __restrict__ xb0,
                                               const float* __restrict__ W1,
                                               const float* __restrict__ W2,
                                               const float* __restrict__ W3,
                                               ushort* __restrict__ Wb, int n, int nbCvt) {
    if ((int)blockIdx.x < nbCvt) {
        int i = blockIdx.x * 256 + threadIdx.x;
        int tot = (n + 1) * 16;
        if (i >= tot) return;
        if (i >= n * 16) {  // pad row n: zero in both gather sources
            g0[i] = make_uint2(0u, 0u);
            g1[i] = make_uint2(0u, 0u);
            return;
        }
        int node = i >> 4;
        float s = dis[node];
        float4 v = ((const float4*)x)[i];
        xb0[i] = make_uint2(pack2(v.x, v.y), pack2(v.z, v.w));
        g0[i]  = make_uint2(pack2(s * v.x, s * v.y), pack2(s * v.z, s * v.w));
        return;
    }
    int idx = ((int)blockIdx.x - nbCvt) * 256 + threadIdx.x;
    if (idx >= (24 + 24 + 12) * 64) return;
    const float* W; int OUTC, NCT, f; ushort* dst;
    if (idx < 24 * 64)      { W = W1; OUTC = 64; NCT = 4; dst = Wb;            f = idx >> 6; }
    else if (idx < 48 * 64) { W = W2; OUTC = 64; NCT = 4; dst = Wb + 24 * 512; f = (idx >> 6) - 24; }
    else                    { W = W3; OUTC = 32; NCT = 2; dst = Wb + 48 * 512; f = (idx >> 6) - 48; }
    int l = idx & 63;
    int ks = f / NCT, ct = f - ks * NCT;
    int col = ct * 16 + (l & 15);
    int k0 = ks * 32 + (l >> 4) * 8;
    unsigned pk[4];
    for (int jj = 0; jj < 4; jj++) {
        unsigned lohi[2];
        for (int h = 0; h < 2; h++) {
            int k = k0 + jj * 2 + h;
            int seg = k >> 6, r = k & 63;
            float v;
            if (seg == 0)      v = W[r * OUTC + col] - W[(128 + r) * OUTC + col];
            else if (seg == 1) v = W[(64 + r) * OUTC + col];
            else               v = 2.0f * W[(128 + r) * OUTC + col];
            lohi[h] = bfr(v);
        }
        pk[jj] = lohi[0] | (lohi[1] << 16);
    }
    *(uint4*)(dst + ((size_t)f * 64 + l) * 8) = make_uint4(pk[0], pk[1], pk[2], pk[3]);
}

// ---------------- propagation ----------------

// out[d][:] = -dis[d] * sum_{e:dst=d} gsrc[src_e][:]   (gsrc bf16 = dis*h)
// 16-lane group per node (4 nodes/wave): each lane owns 4 features across ALL
// the node's edges -> no cross-lane reduce, no masks (lists padded to x4 with
// the zero row n). int4 index broadcast + 4 gathers + 16 adds per step.
template <bool WG>
__global__ void __launch_bounds__(256) k_prop(const uint2* __restrict__ gsrc,
                                              const unsigned* __restrict__ cnt,
                                              const int* __restrict__ slot,
                                              const float* __restrict__ dis,
                                              uint2* __restrict__ xbout,
                                              uint2* __restrict__ gout, int n, int CAP) {
    const int j = threadIdx.x & 15;                       // feature quad (uint2 = 4 bf16)
    const int node = blockIdx.x * 16 + (threadIdx.x >> 4);
    if (node >= n) return;

    int m = (int)cnt[node]; if (m > CAP) m = CAP;
    int m4 = (m + 3) & ~3;  if (m4 > CAP) m4 = CAP;
    const int* __restrict__ base = slot + (size_t)node * CAP;

    float ax = 0.0f, ay = 0.0f, az = 0.0f, aw = 0.0f;
    for (int e = 0; e < m4; e += 4) {
        int4 q = *(const int4*)(base + e);                // broadcast within group
        uint2 v0 = gsrc[(size_t)q.x * 16 + j];
        uint2 v1 = gsrc[(size_t)q.y * 16 + j];
        uint2 v2 = gsrc[(size_t)q.z * 16 + j];
        uint2 v3 = gsrc[(size_t)q.w * 16 + j];
        ax += ubf_lo(v0.x); ay += ubf_hi(v0.x); az += ubf_lo(v0.y); aw += ubf_hi(v0.y);
        ax += ubf_lo(v1.x); ay += ubf_hi(v1.x); az += ubf_lo(v1.y); aw += ubf_hi(v1.y);
        ax += ubf_lo(v2.x); ay += ubf_hi(v2.x); az += ubf_lo(v2.y); aw += ubf_hi(v2.y);
        ax += ubf_lo(v3.x); ay += ubf_hi(v3.x); az += ubf_lo(v3.y); aw += ubf_hi(v3.y);
    }
    float s = dis[node];
    float fx = -s * ax, fy = -s * ay, fz = -s * az, fw = -s * aw;
    xbout[(size_t)node * 16 + j] = make_uint2(pack2(fx, fy), pack2(fz, fw));
    if (WG)
        gout[(size_t)node * 16 + j] =
            make_uint2(pack2(s * fx, s * fy), pack2(s * fz, s * fw));
}

// ---------------- MFMA GEMM (unchanged from round 10) ----------------

template <int NCT>
__device__ __forceinline__ void mm_seg(const ushort* __restrict__ Xp,
                                       const ushort* __restrict__ Wb, int ks0, int l,
                                       int rA0, int rA1, int koff, f32x4* c0, f32x4* c1) {
#pragma unroll
    for (int kt = 0; kt < 2; kt++) {
        bf16x8 a0 = *(const bf16x8*)(Xp + (size_t)rA0 * 64 + kt * 32 + koff);
        bf16x8 a1 = *(const bf16x8*)(Xp + (size_t)rA1 * 64 + kt * 32 + koff);
        int ks = ks0 + kt;
#pragma unroll
        for (int ct = 0; ct < NCT; ct++) {
            bf16x8 b = *(const bf16x8*)(Wb + ((size_t)(ks * NCT + ct) * 64 + l) * 8);
            c0[ct] = __builtin_amdgcn_mfma_f32_16x16x32_bf16(a0, b, c0[ct], 0, 0, 0);
            c1[ct] = __builtin_amdgcn_mfma_f32_16x16x32_bf16(a1, b, c1[ct], 0, 0, 0);
        }
    }
}

// 1 wave/block, 32 rows x OUTC cols, K = 192. C/D layout: col=lane&15, row=(lane>>4)*4+reg.
template <int NCT, bool RELU, bool WG>
__global__ void __launch_bounds__(64, 4) k_mm(const ushort* __restrict__ X0,
                                              const ushort* __restrict__ X1,
                                              const ushort* __restrict__ X2,
                                              const ushort* __restrict__ Wb,
                                              const float* __restrict__ bias,
                                              const float* __restrict__ dis,
                                              float* __restrict__ outf,
                                              ushort* __restrict__ xbout,
                                              ushort* __restrict__ gout, int n) {
    constexpr int OUTC = NCT * 16;
    const int l = threadIdx.x & 63;
    const int r0 = blockIdx.x * 32;
    if (r0 >= n) return;
    const int lm = l & 15, lh = l >> 4;
    const int rA0 = (r0 + lm < n) ? r0 + lm : n - 1;
    const int rA1 = (r0 + 16 + lm < n) ? r0 + 16 + lm : n - 1;
    const int koff = lh * 8;

    f32x4 c0[NCT], c1[NCT];
#pragma unroll
    for (int ct = 0; ct < NCT; ct++) {
        float bv = bias[ct * 16 + lm];
        f32x4 cv = {bv, bv, bv, bv};
        c0[ct] = cv;
        c1[ct] = cv;
    }

    mm_seg<NCT>(X0, Wb, 0, l, rA0, rA1, koff, c0, c1);
    mm_seg<NCT>(X1, Wb, 2, l, rA0, rA1, koff, c0, c1);
    mm_seg<NCT>(X2, Wb, 4, l, rA0, rA1, koff, c0, c1);

#pragma unroll
    for (int half = 0; half < 2; half++) {
        int rbase = r0 + half * 16 + lh * 4;
#pragma unroll
        for (int ct = 0; ct < NCT; ct++) {
            int col = ct * 16 + lm;
#pragma unroll
            for (int r = 0; r < 4; r++) {
                int row = rbase + r;
                if (row < n) {
                    float v = half ? c1[ct][r] : c0[ct][r];
                    if (RELU) v = fmaxf(v, 0.0f);
                    if (WG) {
                        float s = dis[row];
                        xbout[(size_t)row * OUTC + col] = (ushort)bfr(v);
                        gout[(size_t)row * OUTC + col] = (ushort)bfr(s * v);
                    } else {
                        outf[(size_t)row * OUTC + col] = v;
                    }
                }
            }
        }
    }
}

// ---------------- launcher ----------------

extern "C" void kernel_launch(void* const* d_in, const int* in_sizes, int n_in,
                              void* d_out, int out_size, void* d_ws, size_t ws_size,
                              hipStream_t stream) {
    const float* x  = (const float*)d_in[0];
    const int*   ei = (const int*)d_in[1];
    const float* W1 = (const float*)d_in[2];
    const float* b1 = (const float*)d_in[3];
    const float* W2 = (const float*)d_in[4];
    const float* b2 = (const float*)d_in[5];
    const float* W3 = (const float*)d_in[6];
    const float* b3 = (const float*)d_in[7];
    float* out = (float*)d_out;

    const int n = in_sizes[0] / 64;
    const int E = in_sizes[1] / 2;
    const int NW = (n + 3) >> 2;
    const int chunk = (E + NB - 1) / NB;

    char* wsp = (char*)d_ws;
    size_t off = 0;
    auto alloc = [&](size_t bytes) -> char* {
        char* p = wsp + off;
        off += (bytes + 255) & ~(size_t)255;
        return p;
    };
    float* dis     = (float*)alloc((size_t)n * 4);
    unsigned* cnt  = (unsigned*)alloc((size_t)n * 4);
    const size_t XB  = (size_t)n * 64 * 2;        // bf16 feature buffer
    const size_t XBP = (size_t)(n + 1) * 64 * 2;  // +1 zero pad row (gather sources)
    ushort* xb0 = (ushort*)alloc(XB);
    ushort* xbA = (ushort*)alloc(XB);
    ushort* xbB = (ushort*)alloc(XB);
    ushort* xbC = (ushort*)alloc(XB);
    ushort* xbD = (ushort*)alloc(XB);
    ushort* g0  = (ushort*)alloc(XBP);
    ushort* g1  = (ushort*)alloc(XBP);
    ushort* Wb  = (ushort*)alloc((size_t)60 * 512 * 2);

    // build temporaries alias bf16 buffers (each NB*NW*4 = 6.4 MB <= 6.4 MB):
    // baseM over xbA, partialS over xbC, partialD over g0 — all dead before
    // their aliased buffers are first written (k_setup / props / k_mm).
    unsigned* baseM    = (unsigned*)xbA;
    unsigned* partialS = (unsigned*)xbC;
    unsigned* partialD = (unsigned*)g0;

    size_t leftover = (ws_size > off) ? (ws_size - off) : 0;
    int CAP = (int)(leftover / ((size_t)n * 4));
    if (CAP > 64) CAP = 64;
    if (CAP < 16) CAP = 16;
    int* slot = (int*)alloc((size_t)n * CAP * 4);

    const int nbCvt   = ((n + 1) * 16 + 255) / 256;
    const int nb_setup = nbCvt + (60 * 64 + 255) / 256;
    const int nb_red  = (NW + 255) / 256;
    const int nb_prop = (n + 15) / 16;
    const int nb_mm   = (n + 31) / 32;

    k_hist<<<NB, 256, 0, stream>>>(ei, E, chunk, NW, partialS, partialD);
    k_red<<<nb_red, 256, 0, stream>>>(partialS, partialD, baseM, NW, n, dis, cnt, slot, CAP);
    k_scat<<<NB, 256, 0, stream>>>(ei, E, chunk, NW, baseM, slot, CAP);
    k_setup<<<nb_setup, 256, 0, stream>>>(x, dis, (uint2*)g0, (uint2*)g1, (uint2*)xb0,
                                          W1, W2, W3, Wb, n, nbCvt);

    // layer 1
    k_prop<true><<<nb_prop, 256, 0, stream>>>((uint2*)g0, cnt, slot, dis, (uint2*)xbA,
                                              (uint2*)g1, n, CAP);
    k_prop<false><<<nb_prop, 256, 0, stream>>>((uint2*)g1, cnt, slot, dis, (uint2*)xbB,
                                               nullptr, n, CAP);
    k_mm<4, true, true><<<nb_mm, 64, 0, stream>>>(xb0, xbA, xbB, Wb, b1, dis, nullptr,
                                                  xbC, g0, n);

    // layer 2
    k_prop<true><<<nb_prop, 256, 0, stream>>>((uint2*)g0, cnt, slot, dis, (uint2*)xbA,
                                              (uint2*)g1, n, CAP);
    k_prop<false><<<nb_prop, 256, 0, stream>>>((uint2*)g1, cnt, slot, dis, (uint2*)xbB,
                                               nullptr, n, CAP);
    k_mm<4, true, true><<<nb_mm, 64, 0, stream>>>(xbC, xbA, xbB, Wb + 24 * 512, b2, dis,
                                                  nullptr, xbD, g0, n);

    // layer 3 (32 cols, no relu, f32 out)
    k_prop<true><<<nb_prop, 256, 0, stream>>>((uint2*)g0, cnt, slot, dis, (uint2*)xbA,
                                              (uint2*)g1, n, CAP);
    k_prop<false><<<nb_prop, 256, 0, stream>>>((uint2*)g1, cnt, slot, dis, (uint2*)xbB,
                                               nullptr, n, CAP);
    k_mm<2, false, false><<<nb_mm, 64, 0, stream>>>(xbD, xbA, xbB, Wb + 48 * 512, b3, dis,
                                                    out, nullptr, nullptr, n);
}

// Round 12
// 187.697 us; speedup vs baseline: 1.7401x; 1.0449x over previous
//
#include <hip/hip_runtime.h>

#define NB 128        // partition blocks for the graph build
#define NWMAX 16384   // max packed words (n <= 65532); n=50000 -> NW=12500

typedef __attribute__((ext_vector_type(8))) short bf16x8;
typedef __attribute__((ext_vector_type(4))) float f32x4;

// bf16 round-to-nearest-even helpers
__device__ __forceinline__ unsigned bfr(float x) {
    unsigned u = __float_as_uint(x);
    return (u + 0x7FFFu + ((u >> 16) & 1u)) >> 16;
}
__device__ __forceinline__ unsigned pack2(float lo, float hi) {
    return bfr(lo) | (bfr(hi) << 16);
}
__device__ __forceinline__ float ubf_lo(unsigned q) { return __uint_as_float(q << 16); }
__device__ __forceinline__ float ubf_hi(unsigned q) { return __uint_as_float(q & 0xFFFF0000u); }

// ---------------- graph build (atomic-free, 3 passes) ----------------

__global__ void __launch_bounds__(256) k_hist(const int* __restrict__ ei, int E, int chunk,
                                              int NW, unsigned* __restrict__ partialS,
                                              unsigned* __restrict__ partialD) {
    __shared__ unsigned lS[NWMAX];
    __shared__ unsigned lD[NWMAX];
    for (int w = threadIdx.x; w < NW; w += 256) { lS[w] = 0u; lD[w] = 0u; }
    __syncthreads();
    int e0 = blockIdx.x * chunk;
    int e1 = e0 + chunk; if (e1 > E) e1 = E;
    for (int e = e0 + threadIdx.x; e < e1; e += 256) {
        int s = ei[e], d = ei[E + e];
        atomicAdd(&lS[s >> 2], 1u << ((s & 3) * 8));
        atomicAdd(&lD[d >> 2], 1u << ((d & 3) * 8));
    }
    __syncthreads();
    unsigned* pS = partialS + (size_t)blockIdx.x * NW;
    unsigned* pD = partialD + (size_t)blockIdx.x * NW;
    for (int w = threadIdx.x; w < NW; w += 256) { pS[w] = lS[w]; pD[w] = lD[w]; }
}

// Per word (4 nodes): deg -> dis; cnt; per-block exclusive base bytes.
// Also pads each slot list to a multiple of 4 with src = n (the zero row).
__global__ void __launch_bounds__(256) k_red(const unsigned* __restrict__ partialS,
                                             const unsigned* __restrict__ partialD,
                                             unsigned* __restrict__ baseM, int NW, int n,
                                             float* __restrict__ dis,
                                             unsigned* __restrict__ cnt,
                                             int* __restrict__ slot, int CAP) {
    int w = blockIdx.x * 256 + threadIdx.x;
    if (w >= NW) return;
    unsigned s0 = 0, s1 = 0, s2 = 0, s3 = 0;
    unsigned c0 = 0, c1 = 0, c2 = 0, c3 = 0;
#pragma unroll 8
    for (int b = 0; b < NB; b++) {
        unsigned vs = partialS[(size_t)b * NW + w];
        unsigned vd = partialD[(size_t)b * NW + w];
        baseM[(size_t)b * NW + w] = c0 | (c1 << 8) | (c2 << 16) | (c3 << 24);
        s0 += vs & 0xFF; s1 += (vs >> 8) & 0xFF; s2 += (vs >> 16) & 0xFF; s3 += vs >> 24;
        c0 += vd & 0xFF; c1 += (vd >> 8) & 0xFF; c2 += (vd >> 16) & 0xFF; c3 += vd >> 24;
    }
    unsigned ss[4] = {s0, s1, s2, s3}, cc[4] = {c0, c1, c2, c3};
    int node0 = w * 4;
    if (node0 + 3 < n) {
        ((float4*)dis)[w] = make_float4(s0 ? 1.0f / sqrtf((float)s0) : 0.0f,
                                        s1 ? 1.0f / sqrtf((float)s1) : 0.0f,
                                        s2 ? 1.0f / sqrtf((float)s2) : 0.0f,
                                        s3 ? 1.0f / sqrtf((float)s3) : 0.0f);
        ((uint4*)cnt)[w] = make_uint4(c0, c1, c2, c3);
    } else {
        for (int j = 0; j < 4 && node0 + j < n; j++) {
            dis[node0 + j] = ss[j] ? 1.0f / sqrtf((float)ss[j]) : 0.0f;
            cnt[node0 + j] = cc[j];
        }
    }
#pragma unroll
    for (int j = 0; j < 4; j++) {
        int node = node0 + j;
        if (node >= n) break;
        int c = (int)cc[j]; if (c > CAP) c = CAP;
        int c4 = (c + 3) & ~3; if (c4 > CAP) c4 = CAP;
        for (int e = c; e < c4; e++) slot[(size_t)node * CAP + e] = n;
    }
}

__global__ void __launch_bounds__(256) k_scat(const int* __restrict__ ei, int E, int chunk,
                                              int NW, const unsigned* __restrict__ baseM,
                                              int* __restrict__ slot, int CAP) {
    __shared__ unsigned cur[NWMAX];
    __shared__ unsigned bs[NWMAX];
    const unsigned* bRow = baseM + (size_t)blockIdx.x * NW;
    for (int w = threadIdx.x; w < NW; w += 256) { cur[w] = 0u; bs[w] = bRow[w]; }
    __syncthreads();
    int e0 = blockIdx.x * chunk;
    int e1 = e0 + chunk; if (e1 > E) e1 = E;
    for (int e = e0 + threadIdx.x; e < e1; e += 256) {
        int s = ei[e], d = ei[E + e];
        int w = d >> 2, sh = (d & 3) * 8;
        unsigned rank = (atomicAdd(&cur[w], 1u << sh) >> sh) & 0xFF;
        unsigned pos = ((bs[w] >> sh) & 0xFF) + rank;
        if (pos < (unsigned)CAP) slot[(size_t)d * CAP + pos] = s;
    }
}

// ---------------- setup: cvt (+ zero pad row) and W fragment swizzle, fused ----------------

__global__ void __launch_bounds__(256) k_setup(const float* __restrict__ x,
                                               const float* __restrict__ dis,
                                               uint2* __restrict__ g0,
                                               uint2* __restrict__ g1,
                                               uint2* __restrict__ xb0,
                                               const float* __restrict__ W1,
                                               const float* __restrict__ W2,
                                               const float* __restrict__ W3,
                                               ushort* __restrict__ Wb, int n, int nbCvt) {
    if ((int)blockIdx.x < nbCvt) {
        int i = blockIdx.x * 256 + threadIdx.x;
        int tot = (n + 1) * 16;
        if (i >= tot) return;
        if (i >= n * 16) {  // pad row n: zero in both gather sources
            g0[i] = make_uint2(0u, 0u);
            g1[i] = make_uint2(0u, 0u);
            return;
        }
        int node = i >> 4;
        float s = dis[node];
        float4 v = ((const float4*)x)[i];
        xb0[i] = make_uint2(pack2(v.x, v.y), pack2(v.z, v.w));
        g0[i]  = make_uint2(pack2(s * v.x, s * v.y), pack2(s * v.z, s * v.w));
        return;
    }
    int idx = ((int)blockIdx.x - nbCvt) * 256 + threadIdx.x;
    if (idx >= (24 + 24 + 12) * 64) return;
    const float* W; int OUTC, NCT, f; ushort* dst;
    if (idx < 24 * 64)      { W = W1; OUTC = 64; NCT = 4; dst = Wb;            f = idx >> 6; }
    else if (idx < 48 * 64) { W = W2; OUTC = 64; NCT = 4; dst = Wb + 24 * 512; f = (idx >> 6) - 24; }
    else                    { W = W3; OUTC = 32; NCT = 2; dst = Wb + 48 * 512; f = (idx >> 6) - 48; }
    int l = idx & 63;
    int ks = f / NCT, ct = f - ks * NCT;
    int col = ct * 16 + (l & 15);
    int k0 = ks * 32 + (l >> 4) * 8;
    unsigned pk[4];
    for (int jj = 0; jj < 4; jj++) {
        unsigned lohi[2];
        for (int h = 0; h < 2; h++) {
            int k = k0 + jj * 2 + h;
            int seg = k >> 6, r = k & 63;
            float v;
            if (seg == 0)      v = W[r * OUTC + col] - W[(128 + r) * OUTC + col];
            else if (seg == 1) v = W[(64 + r) * OUTC + col];
            else               v = 2.0f * W[(128 + r) * OUTC + col];
            lohi[h] = bfr(v);
        }
        pk[jj] = lohi[0] | (lohi[1] << 16);
    }
    *(uint4*)(dst + ((size_t)f * 64 + l) * 8) = make_uint4(pk[0], pk[1], pk[2], pk[3]);
}

// ---------------- propagation ----------------

// out[d][:] = -dis[d] * sum_{e:dst=d} gsrc[src_e][:]   (gsrc bf16 = dis*h)
// 8-lane group per node (8 nodes/wave, 32/block): lane owns an OCTET of
// features (uint4 = 8 bf16 = 16 B, the coalescing sweet spot). One wave
// iteration covers 32 edges with 5 VMEM instr (vs 16 edges in round 11).
// Lists padded to x4 with the zero row n -> no masks; 8-edge main loop
// keeps 8 gathers in flight.
template <bool WG>
__global__ void __launch_bounds__(256) k_prop(const uint4* __restrict__ gsrc,
                                              const unsigned* __restrict__ cnt,
                                              const int* __restrict__ slot,
                                              const float* __restrict__ dis,
                                              uint4* __restrict__ xbout,
                                              uint4* __restrict__ gout, int n, int CAP) {
    const int j = threadIdx.x & 7;                        // feature octet
    const int node = blockIdx.x * 32 + (threadIdx.x >> 3);
    if (node >= n) return;

    int m = (int)cnt[node]; if (m > CAP) m = CAP;
    int m4 = (m + 3) & ~3;  if (m4 > CAP) m4 = CAP;
    const int* __restrict__ base = slot + (size_t)node * CAP;

    float a0 = 0.f, a1 = 0.f, a2 = 0.f, a3 = 0.f, a4 = 0.f, a5 = 0.f, a6 = 0.f, a7 = 0.f;

#define ACC(v)                                                                \
    do {                                                                      \
        a0 += ubf_lo((v).x); a1 += ubf_hi((v).x);                             \
        a2 += ubf_lo((v).y); a3 += ubf_hi((v).y);                             \
        a4 += ubf_lo((v).z); a5 += ubf_hi((v).z);                             \
        a6 += ubf_lo((v).w); a7 += ubf_hi((v).w);                             \
    } while (0)

    int e = 0;
    for (; e + 8 <= m4; e += 8) {
        int4 q0 = *(const int4*)(base + e);
        int4 q1 = *(const int4*)(base + e + 4);
        uint4 v0 = gsrc[(size_t)q0.x * 8 + j];
        uint4 v1 = gsrc[(size_t)q0.y * 8 + j];
        uint4 v2 = gsrc[(size_t)q0.z * 8 + j];
        uint4 v3 = gsrc[(size_t)q0.w * 8 + j];
        uint4 v4 = gsrc[(size_t)q1.x * 8 + j];
        uint4 v5 = gsrc[(size_t)q1.y * 8 + j];
        uint4 v6 = gsrc[(size_t)q1.z * 8 + j];
        uint4 v7 = gsrc[(size_t)q1.w * 8 + j];
        ACC(v0); ACC(v1); ACC(v2); ACC(v3);
        ACC(v4); ACC(v5); ACC(v6); ACC(v7);
    }
    if (e < m4) {
        int4 q = *(const int4*)(base + e);
        uint4 v0 = gsrc[(size_t)q.x * 8 + j];
        uint4 v1 = gsrc[(size_t)q.y * 8 + j];
        uint4 v2 = gsrc[(size_t)q.z * 8 + j];
        uint4 v3 = gsrc[(size_t)q.w * 8 + j];
        ACC(v0); ACC(v1); ACC(v2); ACC(v3);
    }
#undef ACC

    float s = dis[node];
    float f0 = -s * a0, f1 = -s * a1, f2 = -s * a2, f3 = -s * a3;
    float f4 = -s * a4, f5 = -s * a5, f6 = -s * a6, f7 = -s * a7;
    xbout[(size_t)node * 8 + j] =
        make_uint4(pack2(f0, f1), pack2(f2, f3), pack2(f4, f5), pack2(f6, f7));
    if (WG)
        gout[(size_t)node * 8 + j] =
            make_uint4(pack2(s * f0, s * f1), pack2(s * f2, s * f3),
                       pack2(s * f4, s * f5), pack2(s * f6, s * f7));
}

// ---------------- MFMA GEMM (unchanged from round 10) ----------------

template <int NCT>
__device__ __forceinline__ void mm_seg(const ushort* __restrict__ Xp,
                                       const ushort* __restrict__ Wb, int ks0, int l,
                                       int rA0, int rA1, int koff, f32x4* c0, f32x4* c1) {
#pragma unroll
    for (int kt = 0; kt < 2; kt++) {
        bf16x8 a0 = *(const bf16x8*)(Xp + (size_t)rA0 * 64 + kt * 32 + koff);
        bf16x8 a1 = *(const bf16x8*)(Xp + (size_t)rA1 * 64 + kt * 32 + koff);
        int ks = ks0 + kt;
#pragma unroll
        for (int ct = 0; ct < NCT; ct++) {
            bf16x8 b = *(const bf16x8*)(Wb + ((size_t)(ks * NCT + ct) * 64 + l) * 8);
            c0[ct] = __builtin_amdgcn_mfma_f32_16x16x32_bf16(a0, b, c0[ct], 0, 0, 0);
            c1[ct] = __builtin_amdgcn_mfma_f32_16x16x32_bf16(a1, b, c1[ct], 0, 0, 0);
        }
    }
}

// 1 wave/block, 32 rows x OUTC cols, K = 192. C/D layout: col=lane&15, row=(lane>>4)*4+reg.
template <int NCT, bool RELU, bool WG>
__global__ void __launch_bounds__(64, 4) k_mm(const ushort* __restrict__ X0,
                                              const ushort* __restrict__ X1,
                                              const ushort* __restrict__ X2,
                                              const ushort* __restrict__ Wb,
                                              const float* __restrict__ bias,
                                              const float* __restrict__ dis,
                                              float* __restrict__ outf,
                                              ushort* __restrict__ xbout,
                                              ushort* __restrict__ gout, int n) {
    constexpr int OUTC = NCT * 16;
    const int l = threadIdx.x & 63;
    const int r0 = blockIdx.x * 32;
    if (r0 >= n) return;
    const int lm = l & 15, lh = l >> 4;
    const int rA0 = (r0 + lm < n) ? r0 + lm : n - 1;
    const int rA1 = (r0 + 16 + lm < n) ? r0 + 16 + lm : n - 1;
    const int koff = lh * 8;

    f32x4 c0[NCT], c1[NCT];
#pragma unroll
    for (int ct = 0; ct < NCT; ct++) {
        float bv = bias[ct * 16 + lm];
        f32x4 cv = {bv, bv, bv, bv};
        c0[ct] = cv;
        c1[ct] = cv;
    }

    mm_seg<NCT>(X0, Wb, 0, l, rA0, rA1, koff, c0, c1);
    mm_seg<NCT>(X1, Wb, 2, l, rA0, rA1, koff, c0, c1);
    mm_seg<NCT>(X2, Wb, 4, l, rA0, rA1, koff, c0, c1);

#pragma unroll
    for (int half = 0; half < 2; half++) {
        int rbase = r0 + half * 16 + lh * 4;
#pragma unroll
        for (int ct = 0; ct < NCT; ct++) {
            int col = ct * 16 + lm;
#pragma unroll
            for (int r = 0; r < 4; r++) {
                int row = rbase + r;
                if (row < n) {
                    float v = half ? c1[ct][r] : c0[ct][r];
                    if (RELU) v = fmaxf(v, 0.0f);
                    if (WG) {
                        float s = dis[row];
                        xbout[(size_t)row * OUTC + col] = (ushort)bfr(v);
                        gout[(size_t)row * OUTC + col] = (ushort)bfr(s * v);
                    } else {
                        outf[(size_t)row * OUTC + col] = v;
                    }
                }
            }
        }
    }
}

// ---------------- launcher ----------------

extern "C" void kernel_launch(void* const* d_in, const int* in_sizes, int n_in,
                              void* d_out, int out_size, void* d_ws, size_t ws_size,
                              hipStream_t stream) {
    const float* x  = (const float*)d_in[0];
    const int*   ei = (const int*)d_in[1];
    const float* W1 = (const float*)d_in[2];
    const float* b1 = (const float*)d_in[3];
    const float* W2 = (const float*)d_in[4];
    const float* b2 = (const float*)d_in[5];
    const float* W3 = (const float*)d_in[6];
    const float* b3 = (const float*)d_in[7];
    float* out = (float*)d_out;

    const int n = in_sizes[0] / 64;
    const int E = in_sizes[1] / 2;
    const int NW = (n + 3) >> 2;
    const int chunk = (E + NB - 1) / NB;

    char* wsp = (char*)d_ws;
    size_t off = 0;
    auto alloc = [&](size_t bytes) -> char* {
        char* p = wsp + off;
        off += (bytes + 255) & ~(size_t)255;
        return p;
    };
    float* dis     = (float*)alloc((size_t)n * 4);
    unsigned* cnt  = (unsigned*)alloc((size_t)n * 4);
    const size_t XB  = (size_t)n * 64 * 2;        // bf16 feature buffer
    const size_t XBP = (size_t)(n + 1) * 64 * 2;  // +1 zero pad row (gather sources)
    ushort* xb0 = (ushort*)alloc(XB);
    ushort* xbA = (ushort*)alloc(XB);
    ushort* xbB = (ushort*)alloc(XB);
    ushort* xbC = (ushort*)alloc(XB);
    ushort* xbD = (ushort*)alloc(XB);
    ushort* g0  = (ushort*)alloc(XBP);
    ushort* g1  = (ushort*)alloc(XBP);
    ushort* Wb  = (ushort*)alloc((size_t)60 * 512 * 2);

    // build temporaries alias bf16 buffers (each NB*NW*4 = 6.4 MB <= 6.4 MB):
    // baseM over xbA, partialS over xbC, partialD over g0 — all dead before
    // their aliased buffers are first written (k_setup / props / k_mm).
    unsigned* baseM    = (unsigned*)xbA;
    unsigned* partialS = (unsigned*)xbC;
    unsigned* partialD = (unsigned*)g0;

    size_t leftover = (ws_size > off) ? (ws_size - off) : 0;
    int CAP = (int)(leftover / ((size_t)n * 4));
    if (CAP > 64) CAP = 64;
    if (CAP < 16) CAP = 16;
    int* slot = (int*)alloc((size_t)n * CAP * 4);

    const int nbCvt    = ((n + 1) * 16 + 255) / 256;
    const int nb_setup = nbCvt + (60 * 64 + 255) / 256;
    const int nb_red   = (NW + 255) / 256;
    const int nb_prop  = (n + 31) / 32;
    const int nb_mm    = (n + 31) / 32;

    k_hist<<<NB, 256, 0, stream>>>(ei, E, chunk, NW, partialS, partialD);
    k_red<<<nb_red, 256, 0, stream>>>(partialS, partialD, baseM, NW, n, dis, cnt, slot, CAP);
    k_scat<<<NB, 256, 0, stream>>>(ei, E, chunk, NW, baseM, slot, CAP);
    k_setup<<<nb_setup, 256, 0, stream>>>(x, dis, (uint2*)g0, (uint2*)g1, (uint2*)xb0,
                                          W1, W2, W3, Wb, n, nbCvt);

    // layer 1
    k_prop<true><<<nb_prop, 256, 0, stream>>>((uint4*)g0, cnt, slot, dis, (uint4*)xbA,
                                              (uint4*)g1, n, CAP);
    k_prop<false><<<nb_prop, 256, 0, stream>>>((uint4*)g1, cnt, slot, dis, (uint4*)xbB,
                                               nullptr, n, CAP);
    k_mm<4, true, true><<<nb_mm, 64, 0, stream>>>(xb0, xbA, xbB, Wb, b1, dis, nullptr,
                                                  xbC, g0, n);

    // layer 2
    k_prop<true><<<nb_prop, 256, 0, stream>>>((uint4*)g0, cnt, slot, dis, (uint4*)xbA,
                                              (uint4*)g1, n, CAP);
    k_prop<false><<<nb_prop, 256, 0, stream>>>((uint4*)g1, cnt, slot, dis, (uint4*)xbB,
                                               nullptr, n, CAP);
    k_mm<4, true, true><<<nb_mm, 64, 0, stream>>>(xbC, xbA, xbB, Wb + 24 * 512, b2, dis,
                                                  nullptr, xbD, g0, n);

    // layer 3 (32 cols, no relu, f32 out)
    k_prop<true><<<nb_prop, 256, 0, stream>>>((uint4*)g0, cnt, slot, dis, (uint4*)xbA,
                                              (uint4*)g1, n, CAP);
    k_prop<false><<<nb_prop, 256, 0, stream>>>((uint4*)g1, cnt, slot, dis, (uint4*)xbB,
                                               nullptr, n, CAP);
    k_mm<2, false, false><<<nb_mm, 64, 0, stream>>>(xbD, xbA, xbB, Wb + 48 * 512, b3, dis,
                                                    out, nullptr, nullptr, n);
}

// Round 13
// 173.982 us; speedup vs baseline: 1.8772x; 1.0788x over previous
//
#include <hip/hip_runtime.h>

#define NB 128        // partition blocks for the graph build
#define NWMAX 16384   // max packed words (n <= 65532); n=50000 -> NW=12500
#define LSTR 72       // LDS row stride in shorts (144 B: 16B-aligned, 2-way banks)

typedef __attribute__((ext_vector_type(8))) short bf16x8;
typedef __attribute__((ext_vector_type(4))) float f32x4;

// bf16 round-to-nearest-even helpers
__device__ __forceinline__ unsigned bfr(float x) {
    unsigned u = __float_as_uint(x);
    return (u + 0x7FFFu + ((u >> 16) & 1u)) >> 16;
}
__device__ __forceinline__ unsigned pack2(float lo, float hi) {
    return bfr(lo) | (bfr(hi) << 16);
}
__device__ __forceinline__ float ubf_lo(unsigned q) { return __uint_as_float(q << 16); }
__device__ __forceinline__ float ubf_hi(unsigned q) { return __uint_as_float(q & 0xFFFF0000u); }

// ---------------- graph build ----------------

__global__ void __launch_bounds__(256) k_hist(const int* __restrict__ ei, int E, int chunk,
                                              int NW, unsigned* __restrict__ partialS,
                                              unsigned* __restrict__ partialD) {
    __shared__ unsigned lS[NWMAX];
    __shared__ unsigned lD[NWMAX];
    for (int w = threadIdx.x; w < NW; w += 256) { lS[w] = 0u; lD[w] = 0u; }
    __syncthreads();
    int e0 = blockIdx.x * chunk;
    int e1 = e0 + chunk; if (e1 > E) e1 = E;
    for (int e = e0 + threadIdx.x; e < e1; e += 256) {
        int s = ei[e], d = ei[E + e];
        atomicAdd(&lS[s >> 2], 1u << ((s & 3) * 8));
        atomicAdd(&lD[d >> 2], 1u << ((d & 3) * 8));
    }
    __syncthreads();
    unsigned* pS = partialS + (size_t)blockIdx.x * NW;
    unsigned* pD = partialD + (size_t)blockIdx.x * NW;
    for (int w = threadIdx.x; w < NW; w += 256) { pS[w] = lS[w]; pD[w] = lD[w]; }
}

// Per word (4 nodes): deg -> dis; cnt; per-block exclusive base bytes.
// Pads each slot list to a multiple of 4 with src = n (the zero row).
__global__ void __launch_bounds__(256) k_red(const unsigned* __restrict__ partialS,
                                             const unsigned* __restrict__ partialD,
                                             unsigned* __restrict__ baseM, int NW, int n,
                                             float* __restrict__ dis,
                                             unsigned* __restrict__ cnt,
                                             ushort* __restrict__ slot, int CAP) {
    int w = blockIdx.x * 256 + threadIdx.x;
    if (w >= NW) return;
    unsigned s0 = 0, s1 = 0, s2 = 0, s3 = 0;
    unsigned c0 = 0, c1 = 0, c2 = 0, c3 = 0;
#pragma unroll 8
    for (int b = 0; b < NB; b++) {
        unsigned vs = partialS[(size_t)b * NW + w];
        unsigned vd = partialD[(size_t)b * NW + w];
        baseM[(size_t)b * NW + w] = c0 | (c1 << 8) | (c2 << 16) | (c3 << 24);
        s0 += vs & 0xFF; s1 += (vs >> 8) & 0xFF; s2 += (vs >> 16) & 0xFF; s3 += vs >> 24;
        c0 += vd & 0xFF; c1 += (vd >> 8) & 0xFF; c2 += (vd >> 16) & 0xFF; c3 += vd >> 24;
    }
    unsigned ss[4] = {s0, s1, s2, s3}, cc[4] = {c0, c1, c2, c3};
    int node0 = w * 4;
    if (node0 + 3 < n) {
        ((float4*)dis)[w] = make_float4(s0 ? 1.0f / sqrtf((float)s0) : 0.0f,
                                        s1 ? 1.0f / sqrtf((float)s1) : 0.0f,
                                        s2 ? 1.0f / sqrtf((float)s2) : 0.0f,
                                        s3 ? 1.0f / sqrtf((float)s3) : 0.0f);
        ((uint4*)cnt)[w] = make_uint4(c0, c1, c2, c3);
    } else {
        for (int j = 0; j < 4 && node0 + j < n; j++) {
            dis[node0 + j] = ss[j] ? 1.0f / sqrtf((float)ss[j]) : 0.0f;
            cnt[node0 + j] = cc[j];
        }
    }
#pragma unroll
    for (int j = 0; j < 4; j++) {
        int node = node0 + j;
        if (node >= n) break;
        int c = (int)cc[j]; if (c > CAP) c = CAP;
        int c4 = (c + 3) & ~3; if (c4 > CAP) c4 = CAP;
        for (int e = c; e < c4; e++) slot[(size_t)node * CAP + e] = (ushort)n;
    }
}

// blocks [0,NB): bucket-scatter edges (LDS cursors, no global atomics);
// blocks [NB, gridDim): grid-stride setup (bf16 cvt + pad row + W frag swizzle).
// Both depend only on k_red -> run concurrently on disjoint CUs.
__global__ void __launch_bounds__(256) k_build3(const int* __restrict__ ei, int E, int chunk,
                                                int NW, const unsigned* __restrict__ baseM,
                                                ushort* __restrict__ slot, int CAP,
                                                const float* __restrict__ x,
                                                const float* __restrict__ dis,
                                                uint2* __restrict__ g0,
                                                uint2* __restrict__ g1,
                                                uint2* __restrict__ xb0,
                                                const float* __restrict__ W1,
                                                const float* __restrict__ W2,
                                                const float* __restrict__ W3,
                                                ushort* __restrict__ Wb, int n) {
    __shared__ unsigned cur[NWMAX];
    __shared__ unsigned bs[NWMAX];
    if ((int)blockIdx.x < NB) {  // ---- scatter part ----
        const unsigned* bRow = baseM + (size_t)blockIdx.x * NW;
        for (int w = threadIdx.x; w < NW; w += 256) { cur[w] = 0u; bs[w] = bRow[w]; }
        __syncthreads();
        int e0 = blockIdx.x * chunk;
        int e1 = e0 + chunk; if (e1 > E) e1 = E;
        for (int e = e0 + threadIdx.x; e < e1; e += 256) {
            int s = ei[e], d = ei[E + e];
            int w = d >> 2, sh = (d & 3) * 8;
            unsigned rank = (atomicAdd(&cur[w], 1u << sh) >> sh) & 0xFF;
            unsigned pos = ((bs[w] >> sh) & 0xFF) + rank;
            if (pos < (unsigned)CAP) slot[(size_t)d * CAP + pos] = (ushort)s;
        }
        return;
    }
    // ---- setup part (grid-stride) ----
    int nblk = gridDim.x - NB;
    int bid = (int)blockIdx.x - NB;
    int tot = (n + 1) * 16;
    for (int i = bid * 256 + threadIdx.x; i < tot; i += nblk * 256) {
        if (i >= n * 16) {  // pad row n: zero in both gather sources
            g0[i] = make_uint2(0u, 0u);
            g1[i] = make_uint2(0u, 0u);
            continue;
        }
        int node = i >> 4;
        float s = dis[node];
        float4 v = ((const float4*)x)[i];
        xb0[i] = make_uint2(pack2(v.x, v.y), pack2(v.z, v.w));
        g0[i]  = make_uint2(pack2(s * v.x, s * v.y), pack2(s * v.z, s * v.w));
    }
    for (int idx = bid * 256 + threadIdx.x; idx < (24 + 24 + 12) * 64; idx += nblk * 256) {
        const float* W; int OUTC, NCT, f; ushort* dst; int id = idx;
        if (id < 24 * 64)      { W = W1; OUTC = 64; NCT = 4; dst = Wb;            f = id >> 6; }
        else if (id < 48 * 64) { W = W2; OUTC = 64; NCT = 4; dst = Wb + 24 * 512; f = (id >> 6) - 24; }
        else                   { W = W3; OUTC = 32; NCT = 2; dst = Wb + 48 * 512; f = (id >> 6) - 48; }
        int l = id & 63;
        int ks = f / NCT, ct = f - ks * NCT;
        int col = ct * 16 + (l & 15);
        int k0 = ks * 32 + (l >> 4) * 8;
        unsigned pk[4];
        for (int jj = 0; jj < 4; jj++) {
            unsigned lohi[2];
            for (int h = 0; h < 2; h++) {
                int k = k0 + jj * 2 + h;
                int seg = k >> 6, r = k & 63;
                float v;
                if (seg == 0)      v = W[r * OUTC + col] - W[(128 + r) * OUTC + col];
                else if (seg == 1) v = W[(64 + r) * OUTC + col];
                else               v = 2.0f * W[(128 + r) * OUTC + col];
                lohi[h] = bfr(v);
            }
            pk[jj] = lohi[0] | (lohi[1] << 16);
        }
        *(uint4*)(dst + ((size_t)f * 64 + l) * 8) = make_uint4(pk[0], pk[1], pk[2], pk[3]);
    }
}

// ---------------- gather core (8 lanes/node, uint4 = 8 bf16 feats/lane) ----------------

struct Acc8 { float a0, a1, a2, a3, a4, a5, a6, a7; };

__device__ __forceinline__ void acc8(Acc8& A, uint4 v) {
    A.a0 += ubf_lo(v.x); A.a1 += ubf_hi(v.x);
    A.a2 += ubf_lo(v.y); A.a3 += ubf_hi(v.y);
    A.a4 += ubf_lo(v.z); A.a5 += ubf_hi(v.z);
    A.a6 += ubf_lo(v.w); A.a7 += ubf_hi(v.w);
}

__device__ __forceinline__ Acc8 gather_sum(const uint4* __restrict__ gsrc,
                                           const ushort* __restrict__ base, int m4, int j) {
    Acc8 A = {0.f, 0.f, 0.f, 0.f, 0.f, 0.f, 0.f, 0.f};
    int e = 0;
    for (; e + 8 <= m4; e += 8) {
        uint2 qa = *(const uint2*)(base + e);
        uint2 qb = *(const uint2*)(base + e + 4);
        uint4 v0 = gsrc[(size_t)(qa.x & 0xFFFFu) * 8 + j];
        uint4 v1 = gsrc[(size_t)(qa.x >> 16) * 8 + j];
        uint4 v2 = gsrc[(size_t)(qa.y & 0xFFFFu) * 8 + j];
        uint4 v3 = gsrc[(size_t)(qa.y >> 16) * 8 + j];
        uint4 v4 = gsrc[(size_t)(qb.x & 0xFFFFu) * 8 + j];
        uint4 v5 = gsrc[(size_t)(qb.x >> 16) * 8 + j];
        uint4 v6 = gsrc[(size_t)(qb.y & 0xFFFFu) * 8 + j];
        uint4 v7 = gsrc[(size_t)(qb.y >> 16) * 8 + j];
        acc8(A, v0); acc8(A, v1); acc8(A, v2); acc8(A, v3);
        acc8(A, v4); acc8(A, v5); acc8(A, v6); acc8(A, v7);
    }
    if (e < m4) {
        uint2 qa = *(const uint2*)(base + e);
        uint4 v0 = gsrc[(size_t)(qa.x & 0xFFFFu) * 8 + j];
        uint4 v1 = gsrc[(size_t)(qa.x >> 16) * 8 + j];
        uint4 v2 = gsrc[(size_t)(qa.y & 0xFFFFu) * 8 + j];
        uint4 v3 = gsrc[(size_t)(qa.y >> 16) * 8 + j];
        acc8(A, v0); acc8(A, v1); acc8(A, v2); acc8(A, v3);
    }
    return A;
}

// ---------------- standalone prop (P1 of each layer): writes xbA + g1 ----------------

__global__ void __launch_bounds__(256) k_prop(const uint4* __restrict__ gsrc,
                                              const unsigned* __restrict__ cnt,
                                              const ushort* __restrict__ slot,
                                              const float* __restrict__ dis,
                                              uint4* __restrict__ xbout,
                                              uint4* __restrict__ gout, int n, int CAP) {
    const int j = threadIdx.x & 7;
    const int node = blockIdx.x * 32 + (threadIdx.x >> 3);
    if (node >= n) return;
    int m = (int)cnt[node]; if (m > CAP) m = CAP;
    int m4 = (m + 3) & ~3;  if (m4 > CAP) m4 = CAP;
    Acc8 A = gather_sum(gsrc, slot + (size_t)node * CAP, m4, j);
    float s = dis[node];
    float f0 = -s * A.a0, f1 = -s * A.a1, f2 = -s * A.a2, f3 = -s * A.a3;
    float f4 = -s * A.a4, f5 = -s * A.a5, f6 = -s * A.a6, f7 = -s * A.a7;
    xbout[(size_t)node * 8 + j] =
        make_uint4(pack2(f0, f1), pack2(f2, f3), pack2(f4, f5), pack2(f6, f7));
    gout[(size_t)node * 8 + j] =
        make_uint4(pack2(s * f0, s * f1), pack2(s * f2, s * f3),
                   pack2(s * f4, s * f5), pack2(s * f6, s * f7));
}

// ---------------- fused prop2 + MFMA GEMM ----------------
// Phase 1: 256 thr = 32 nodes x 8 lanes compute P2 rows -> LDS (bf16, stride 72).
// Phase 2: wave wv (< NCT) computes 32 rows x 16 cols (col-tile wv) via MFMA;
//          K-segments: X0, X1 from global bf16; P2 from LDS.
// P2 never leaves the block (it is only a GEMM input) -> no global P2 buffer.
template <int NCT, bool RELU, bool WG>
__global__ void __launch_bounds__(256) k_pm(const uint4* __restrict__ gsrc,
                                            const unsigned* __restrict__ cnt,
                                            const ushort* __restrict__ slot,
                                            const float* __restrict__ dis,
                                            const ushort* __restrict__ X0,
                                            const ushort* __restrict__ X1,
                                            const ushort* __restrict__ Wb,
                                            const float* __restrict__ bias,
                                            float* __restrict__ outf,
                                            ushort* __restrict__ xbout,
                                            ushort* __restrict__ gout, int n, int CAP) {
    constexpr int OUTC = NCT * 16;
    __shared__ ushort P2[32 * LSTR];
    const int r0 = blockIdx.x * 32;

    {   // phase 1
        const int j = threadIdx.x & 7;
        const int ni = threadIdx.x >> 3;   // 0..31
        const int node = r0 + ni;
        uint4 pk = make_uint4(0u, 0u, 0u, 0u);
        if (node < n) {
            int m = (int)cnt[node]; if (m > CAP) m = CAP;
            int m4 = (m + 3) & ~3;  if (m4 > CAP) m4 = CAP;
            Acc8 A = gather_sum(gsrc, slot + (size_t)node * CAP, m4, j);
            float s = dis[node];
            pk = make_uint4(pack2(-s * A.a0, -s * A.a1), pack2(-s * A.a2, -s * A.a3),
                            pack2(-s * A.a4, -s * A.a5), pack2(-s * A.a6, -s * A.a7));
        }
        *(uint4*)&P2[ni * LSTR + j * 8] = pk;
    }
    __syncthreads();

    const int wv = threadIdx.x >> 6;
    if (wv >= NCT) return;
    const int ct = wv;
    const int l = threadIdx.x & 63;
    const int lm = l & 15, lh = l >> 4, koff = lh * 8;
    const int rA0 = (r0 + lm < n) ? r0 + lm : n - 1;
    const int rA1 = (r0 + 16 + lm < n) ? r0 + 16 + lm : n - 1;

    float bv = bias[ct * 16 + lm];
    f32x4 c0 = {bv, bv, bv, bv}, c1 = c0;

#pragma unroll
    for (int kt = 0; kt < 2; kt++) {  // seg X0: ks 0,1
        bf16x8 a0 = *(const bf16x8*)(X0 + (size_t)rA0 * 64 + kt * 32 + koff);
        bf16x8 a1 = *(const bf16x8*)(X0 + (size_t)rA1 * 64 + kt * 32 + koff);
        bf16x8 b = *(const bf16x8*)(Wb + ((size_t)(kt * NCT + ct) * 64 + l) * 8);
        c0 = __builtin_amdgcn_mfma_f32_16x16x32_bf16(a0, b, c0, 0, 0, 0);
        c1 = __builtin_amdgcn_mfma_f32_16x16x32_bf16(a1, b, c1, 0, 0, 0);
    }
#pragma unroll
    for (int kt = 0; kt < 2; kt++) {  // seg X1: ks 2,3
        bf16x8 a0 = *(const bf16x8*)(X1 + (size_t)rA0 * 64 + kt * 32 + koff);
        bf16x8 a1 = *(const bf16x8*)(X1 + (size_t)rA1 * 64 + kt * 32 + koff);
        bf16x8 b = *(const bf16x8*)(Wb + ((size_t)((2 + kt) * NCT + ct) * 64 + l) * 8);
        c0 = __builtin_amdgcn_mfma_f32_16x16x32_bf16(a0, b, c0, 0, 0, 0);
        c1 = __builtin_amdgcn_mfma_f32_16x16x32_bf16(a1, b, c1, 0, 0, 0);
    }
#pragma unroll
    for (int kt = 0; kt < 2; kt++) {  // seg P2 (LDS): ks 4,5
        bf16x8 a0 = *(const bf16x8*)&P2[lm * LSTR + kt * 32 + koff];
        bf16x8 a1 = *(const bf16x8*)&P2[(16 + lm) * LSTR + kt * 32 + koff];
        bf16x8 b = *(const bf16x8*)(Wb + ((size_t)((4 + kt) * NCT + ct) * 64 + l) * 8);
        c0 = __builtin_amdgcn_mfma_f32_16x16x32_bf16(a0, b, c0, 0, 0, 0);
        c1 = __builtin_amdgcn_mfma_f32_16x16x32_bf16(a1, b, c1, 0, 0, 0);
    }

#pragma unroll
    for (int half = 0; half < 2; half++) {
        int rbase = r0 + half * 16 + lh * 4;
        int col = ct * 16 + lm;
#pragma unroll
        for (int r = 0; r < 4; r++) {
            int row = rbase + r;
            if (row < n) {
                float v = half ? c1[r] : c0[r];
                if (RELU) v = fmaxf(v, 0.0f);
                if (WG) {
                    float s = dis[row];
                    xbout[(size_t)row * OUTC + col] = (ushort)bfr(v);
                    gout[(size_t)row * OUTC + col] = (ushort)bfr(s * v);
                } else {
                    outf[(size_t)row * OUTC + col] = v;
                }
            }
        }
    }
}

// ---------------- launcher ----------------

extern "C" void kernel_launch(void* const* d_in, const int* in_sizes, int n_in,
                              void* d_out, int out_size, void* d_ws, size_t ws_size,
                              hipStream_t stream) {
    const float* x  = (const float*)d_in[0];
    const int*   ei = (const int*)d_in[1];
    const float* W1 = (const float*)d_in[2];
    const float* b1 = (const float*)d_in[3];
    const float* W2 = (const float*)d_in[4];
    const float* b2 = (const float*)d_in[5];
    const float* W3 = (const float*)d_in[6];
    const float* b3 = (const float*)d_in[7];
    float* out = (float*)d_out;

    const int n = in_sizes[0] / 64;
    const int E = in_sizes[1] / 2;
    const int NW = (n + 3) >> 2;
    const int chunk = (E + NB - 1) / NB;

    char* wsp = (char*)d_ws;
    size_t off = 0;
    auto alloc = [&](size_t bytes) -> char* {
        char* p = wsp + off;
        off += (bytes + 255) & ~(size_t)255;
        return p;
    };
    float* dis     = (float*)alloc((size_t)n * 4);
    unsigned* cnt  = (unsigned*)alloc((size_t)n * 4);
    const size_t XB  = (size_t)n * 64 * 2;        // bf16 feature buffer
    const size_t XBP = (size_t)(n + 1) * 64 * 2;  // +1 zero pad row (gather sources)
    ushort* xb0 = (ushort*)alloc(XB);
    ushort* xbA = (ushort*)alloc(XB);
    ushort* xbC = (ushort*)alloc(XB);
    ushort* xbD = (ushort*)alloc(XB);
    ushort* g0  = (ushort*)alloc(XBP);
    ushort* g1  = (ushort*)alloc(XBP);
    ushort* Wb  = (ushort*)alloc((size_t)60 * 512 * 2);

    // build temporaries alias bf16 buffers (each NB*NW*4 = 6.4 MB = XB):
    // baseM over xbA (read during k_build3, xbA written by later k_prop);
    // partialS over xbC, partialD over xbD (dead after k_red; written by k_pm L1/L2).
    unsigned* baseM    = (unsigned*)xbA;
    unsigned* partialS = (unsigned*)xbC;
    unsigned* partialD = (unsigned*)xbD;

    size_t leftover = (ws_size > off) ? (ws_size - off) : 0;
    int CAP = (int)(leftover / ((size_t)n * 2));
    if (CAP > 64) CAP = 64;
    if (CAP < 16) CAP = 16;
    CAP &= ~3;  // multiple of 4 (8 B-aligned uint2 index loads)
    ushort* slot = (ushort*)alloc((size_t)n * CAP * 2);

    const int nb_red  = (NW + 255) / 256;
    const int nb_prop = (n + 31) / 32;

    k_hist<<<NB, 256, 0, stream>>>(ei, E, chunk, NW, partialS, partialD);
    k_red<<<nb_red, 256, 0, stream>>>(partialS, partialD, baseM, NW, n, dis, cnt, slot, CAP);
    k_build3<<<NB + 128, 256, 0, stream>>>(ei, E, chunk, NW, baseM, slot, CAP,
                                           x, dis, (uint2*)g0, (uint2*)g1, (uint2*)xb0,
                                           W1, W2, W3, Wb, n);

    // layer 1: P1 -> (xbA, g1); fused P2+GEMM -> (xbC, g0)
    k_prop<<<nb_prop, 256, 0, stream>>>((uint4*)g0, cnt, slot, dis, (uint4*)xbA,
                                        (uint4*)g1, n, CAP);
    k_pm<4, true, true><<<nb_prop, 256, 0, stream>>>((uint4*)g1, cnt, slot, dis, xb0, xbA,
                                                     Wb, b1, nullptr, xbC, g0, n, CAP);

    // layer 2
    k_prop<<<nb_prop, 256, 0, stream>>>((uint4*)g0, cnt, slot, dis, (uint4*)xbA,
                                        (uint4*)g1, n, CAP);
    k_pm<4, true, true><<<nb_prop, 256, 0, stream>>>((uint4*)g1, cnt, slot, dis, xbC, xbA,
                                                     Wb + 24 * 512, b2, nullptr, xbD, g0,
                                                     n, CAP);

    // layer 3 (32 cols, no relu, f32 out)
    k_prop<<<nb_prop, 256, 0, stream>>>((uint4*)g0, cnt, slot, dis, (uint4*)xbA,
                                        (uint4*)g1, n, CAP);
    k_pm<2, false, false><<<nb_prop, 256, 0, stream>>>((uint4*)g1, cnt, slot, dis, xbD, xbA,
                                                       Wb + 48 * 512, b3, out, nullptr,
                                                       nullptr, n, CAP);
}